// Round 1
// baseline (960.424 us; speedup 1.0000x reference)
//
#include <hip/hip_runtime.h>
#include <hip/hip_fp16.h>

typedef float   f32x4   __attribute__((ext_vector_type(4)));
typedef float   f32x2   __attribute__((ext_vector_type(2)));
typedef short   short8v __attribute__((ext_vector_type(8)));
typedef unsigned short ushort8v __attribute__((ext_vector_type(8)));
typedef int     int2v   __attribute__((ext_vector_type(2)));

#define DEVI static __device__ __forceinline__

DEVI unsigned short f2bf(float f) {
    unsigned int u = __builtin_bit_cast(unsigned int, f);
    u += 0x7FFFu + ((u >> 16) & 1u);   // RNE (inputs finite)
    return (unsigned short)(u >> 16);
}

// ---------------------------------------------------------------------------
// Kernel 1: dequant cache -> bf16, exact requant of cache window rows,
// f16-rounded scales. 1 wave per (b,h,row). rows = 4*16*4096 = 262144.
// ---------------------------------------------------------------------------
__global__ __launch_bounds__(256) void prep_cache_kernel(
    const int* __restrict__ kq, const int* __restrict__ vq,
    const float* __restrict__ ks, const float* __restrict__ vs,
    unsigned int* __restrict__ kcp, unsigned int* __restrict__ vcp,
    float* __restrict__ oktq, float* __restrict__ ovtq,
    float* __restrict__ oksc, float* __restrict__ ovsc) {
    const int row  = blockIdx.x * 4 + (threadIdx.x >> 6);
    const int lane = threadIdx.x & 63;
    const float sk = ks[row], sv = vs[row];
    int2v kv = *(const int2v*)(kq + (size_t)row * 128 + lane * 2);
    int2v vv = *(const int2v*)(vq + (size_t)row * 128 + lane * 2);
    float kx0 = (float)kv[0] * sk, kx1 = (float)kv[1] * sk;
    float vx0 = (float)vv[0] * sv, vx1 = (float)vv[1] * sv;
    kcp[(size_t)row * 64 + lane] = (unsigned)f2bf(kx0) | ((unsigned)f2bf(kx1) << 16);
    vcp[(size_t)row * 64 + lane] = (unsigned)f2bf(vx0) | ((unsigned)f2bf(vx1) << 16);
    float kam = fmaxf(fabsf(kx0), fabsf(kx1));
    float vam = fmaxf(fabsf(vx0), fabsf(vx1));
    #pragma unroll
    for (int off = 1; off < 64; off <<= 1) {
        kam = fmaxf(kam, __shfl_xor(kam, off, 64));
        vam = fmaxf(vam, __shfl_xor(vam, off, 64));
    }
    const int r = row & 4095;
    if (r >= 512) {
        const size_t orow = ((size_t)(row >> 12)) * 4096 + (size_t)(r - 512);
        float kscale = fmaxf(kam / 127.0f, 1e-8f);
        float vscale = fmaxf(vam / 127.0f, 1e-8f);
        float kinv = 1.0f / kscale, vinv = 1.0f / vscale;
        f32x2 ko, vo;
        ko[0] = fminf(fmaxf(rintf(kx0 * kinv), -127.f), 127.f);
        ko[1] = fminf(fmaxf(rintf(kx1 * kinv), -127.f), 127.f);
        vo[0] = fminf(fmaxf(rintf(vx0 * vinv), -127.f), 127.f);
        vo[1] = fminf(fmaxf(rintf(vx1 * vinv), -127.f), 127.f);
        *(f32x2*)(oktq + orow * 128 + lane * 2) = ko;
        *(f32x2*)(ovtq + orow * 128 + lane * 2) = vo;
        if (lane == 0) {
            oksc[orow] = __half2float(__float2half(kscale));
            ovsc[orow] = __half2float(__float2half(vscale));
        }
    }
}

// ---------------------------------------------------------------------------
// Kernel 2: GEMM  C[m][n] = sum_k A[m][k] * W[n][k]   (M=N=K=2048)
// MODE 0: write head-split ((b*16+h)*512+i)*128+d ; MODE 1: plain row-major.
// BM=BN=128, BK=32, 256 threads (4 waves, 2x2 of 64x64), 16x16x32 bf16 MFMA.
// ---------------------------------------------------------------------------
template <int MODE>
__global__ __launch_bounds__(256) void gemm_bt_kernel(
    const float* __restrict__ A, const float* __restrict__ Bw,
    float* __restrict__ C) {
    __shared__ unsigned short As[128][40];
    __shared__ unsigned short Bs[128][40];
    const int tid  = threadIdx.x;
    const int bm   = blockIdx.x & 15, bn = blockIdx.x >> 4;
    const int m0   = bm * 128, n0 = bn * 128;
    const int lane = tid & 63, w = tid >> 6;
    const int wm   = (w >> 1) * 64, wn = (w & 1) * 64;
    const int r16  = lane & 15, kb = lane >> 4;

    f32x4 acc[4][4] = {};

    for (int k0 = 0; k0 < 2048; k0 += 32) {
        __syncthreads();
        #pragma unroll
        for (int s = 0; s < 4; ++s) {
            int flat = tid + s * 256;             // 1024 float4s
            int row = flat >> 3, col = (flat & 7) << 2;
            f32x4 av = *(const f32x4*)(A  + (size_t)(m0 + row) * 2048 + k0 + col);
            f32x4 bv = *(const f32x4*)(Bw + (size_t)(n0 + row) * 2048 + k0 + col);
            As[row][col+0]=f2bf(av[0]); As[row][col+1]=f2bf(av[1]);
            As[row][col+2]=f2bf(av[2]); As[row][col+3]=f2bf(av[3]);
            Bs[row][col+0]=f2bf(bv[0]); Bs[row][col+1]=f2bf(bv[1]);
            Bs[row][col+2]=f2bf(bv[2]); Bs[row][col+3]=f2bf(bv[3]);
        }
        __syncthreads();
        short8v af[4], bf[4];
        #pragma unroll
        for (int mf = 0; mf < 4; ++mf)
            af[mf] = __builtin_bit_cast(short8v, *(const ushort8v*)&As[wm + mf*16 + r16][kb*8]);
        #pragma unroll
        for (int nf = 0; nf < 4; ++nf)
            bf[nf] = __builtin_bit_cast(short8v, *(const ushort8v*)&Bs[wn + nf*16 + r16][kb*8]);
        #pragma unroll
        for (int mf = 0; mf < 4; ++mf)
            #pragma unroll
            for (int nf = 0; nf < 4; ++nf)
                acc[mf][nf] = __builtin_amdgcn_mfma_f32_16x16x32_bf16(af[mf], bf[nf], acc[mf][nf], 0, 0, 0);
    }

    #pragma unroll
    for (int mf = 0; mf < 4; ++mf)
        #pragma unroll
        for (int nf = 0; nf < 4; ++nf)
            #pragma unroll
            for (int v = 0; v < 4; ++v) {
                int mg = m0 + wm + mf * 16 + kb * 4 + v;
                int ng = n0 + wn + nf * 16 + r16;
                float val = acc[mf][nf][v];
                if (MODE == 0) {
                    int b = mg >> 9, i = mg & 511, h = ng >> 7, d = ng & 127;
                    C[(((size_t)b * 16 + h) * 512 + i) * 128 + d] = val;
                } else {
                    C[(size_t)mg * 2048 + ng] = val;
                }
            }
}

// ---------------------------------------------------------------------------
// Kernel 3: flash attention. 512 blocks = (b,h) x 8 q-tiles of 64 rows.
// 4 waves/block, 16 query rows/wave. 64-key tiles; cache part bf16, new f32.
// ---------------------------------------------------------------------------
__global__ __launch_bounds__(256) void attn_kernel(
    const float* __restrict__ qw,
    const unsigned short* __restrict__ kc, const unsigned short* __restrict__ vc,
    const float* __restrict__ kn, const float* __restrict__ vn,
    float* __restrict__ yout) {
    __shared__ unsigned short Ks[64][136];   // [key][d]  (+8 pad)
    __shared__ unsigned short Vt[128][72];   // [d][key]  (+8 pad)
    __shared__ unsigned short Pl[4][16][72]; // per-wave P round-trip

    const int tid = threadIdx.x, lane = tid & 63, w = tid >> 6;
    const int bh = blockIdx.x >> 3, qt = blockIdx.x & 7;
    const int b = bh >> 4, h = bh & 15;
    const int r16 = lane & 15, kb = lane >> 4;
    const float rscale = 0.08838834764831845f;  // 1/sqrt(128)

    // Q fragments (scale folded in)
    const int qrow_frag = qt * 64 + w * 16 + r16;
    const float* qp = qw + ((size_t)bh * 512 + qrow_frag) * 128;
    short8v qf[4];
    #pragma unroll
    for (int f = 0; f < 4; ++f) {
        ushort8v t;
        #pragma unroll
        for (int e = 0; e < 8; ++e) t[e] = f2bf(qp[f * 32 + kb * 8 + e] * rscale);
        qf[f] = __builtin_bit_cast(short8v, t);
    }

    f32x4 Of[8] = {};
    float m_i[4], l_i[4];
    #pragma unroll
    for (int v = 0; v < 4; ++v) { m_i[v] = -3.0e38f; l_i[v] = 0.f; }

    const int ntiles = 65 + qt;
    for (int kt = 0; kt < ntiles; ++kt) {
        __syncthreads();
        if (kt < 64) {
            const unsigned short* ksrc = kc + ((size_t)bh * 4096 + kt * 64) * 128;
            const unsigned short* vsrc = vc + ((size_t)bh * 4096 + kt * 64) * 128;
            #pragma unroll
            for (int s = 0; s < 4; ++s) {
                int flat = (tid + s * 256) << 3;
                int row = flat >> 7, col = flat & 127;
                ushort8v kv8 = *(const ushort8v*)(ksrc + row * 128 + col);
                *(ushort8v*)&Ks[row][col] = kv8;
                ushort8v vv8 = *(const ushort8v*)(vsrc + row * 128 + col);
                #pragma unroll
                for (int e = 0; e < 8; ++e) Vt[col + e][row] = vv8[e];
            }
        } else {
            const float* ksrc = kn + ((size_t)bh * 512 + (kt - 64) * 64) * 128;
            const float* vsrc = vn + ((size_t)bh * 512 + (kt - 64) * 64) * 128;
            #pragma unroll
            for (int s = 0; s < 4; ++s) {
                int flat = (tid + s * 256) << 3;
                int row = flat >> 7, col = flat & 127;
                const float* kp = ksrc + row * 128 + col;
                const float* vp = vsrc + row * 128 + col;
                f32x4 k0 = *(const f32x4*)kp, k1 = *(const f32x4*)(kp + 4);
                f32x4 v0 = *(const f32x4*)vp, v1 = *(const f32x4*)(vp + 4);
                ushort8v t;
                t[0]=f2bf(k0[0]); t[1]=f2bf(k0[1]); t[2]=f2bf(k0[2]); t[3]=f2bf(k0[3]);
                t[4]=f2bf(k1[0]); t[5]=f2bf(k1[1]); t[6]=f2bf(k1[2]); t[7]=f2bf(k1[3]);
                *(ushort8v*)&Ks[row][col] = t;
                Vt[col+0][row]=f2bf(v0[0]); Vt[col+1][row]=f2bf(v0[1]);
                Vt[col+2][row]=f2bf(v0[2]); Vt[col+3][row]=f2bf(v0[3]);
                Vt[col+4][row]=f2bf(v1[0]); Vt[col+5][row]=f2bf(v1[1]);
                Vt[col+6][row]=f2bf(v1[2]); Vt[col+7][row]=f2bf(v1[3]);
            }
        }
        __syncthreads();

        // S = (Q*scale) K^T   : 16 x 64 per wave
        f32x4 Sf[4] = {};
        #pragma unroll
        for (int nf = 0; nf < 4; ++nf)
            #pragma unroll
            for (int ks = 0; ks < 4; ++ks) {
                short8v kf = __builtin_bit_cast(short8v,
                    *(const ushort8v*)&Ks[nf * 16 + r16][ks * 32 + kb * 8]);
                Sf[nf] = __builtin_amdgcn_mfma_f32_16x16x32_bf16(qf[ks], kf, Sf[nf], 0, 0, 0);
            }

        if (kt >= 64) {  // causal mask within the new segment
            const int jn0 = (kt - 64) * 64;
            const int qbase = qt * 64 + w * 16;
            #pragma unroll
            for (int nf = 0; nf < 4; ++nf) {
                int jn = jn0 + nf * 16 + r16;
                #pragma unroll
                for (int v = 0; v < 4; ++v)
                    if (jn > qbase + kb * 4 + v) Sf[nf][v] = -3.0e38f;
            }
        }

        // online softmax (rows live in lanes sharing kb, across r16)
        float alpha[4], rsum[4];
        #pragma unroll
        for (int v = 0; v < 4; ++v) {
            float mx = fmaxf(fmaxf(Sf[0][v], Sf[1][v]), fmaxf(Sf[2][v], Sf[3][v]));
            #pragma unroll
            for (int off = 1; off < 16; off <<= 1) mx = fmaxf(mx, __shfl_xor(mx, off, 64));
            float mnew = fmaxf(m_i[v], mx);
            alpha[v] = __expf(m_i[v] - mnew);
            m_i[v] = mnew;
            rsum[v] = 0.f;
        }
        #pragma unroll
        for (int nf = 0; nf < 4; ++nf)
            #pragma unroll
            for (int v = 0; v < 4; ++v) {
                float p = __expf(Sf[nf][v] - m_i[v]);
                Sf[nf][v] = p;
                rsum[v] += p;
            }
        #pragma unroll
        for (int v = 0; v < 4; ++v) {
            float sm = rsum[v];
            #pragma unroll
            for (int off = 1; off < 16; off <<= 1) sm += __shfl_xor(sm, off, 64);
            l_i[v] = l_i[v] * alpha[v] + sm;
        }
        #pragma unroll
        for (int of = 0; of < 8; ++of)
            #pragma unroll
            for (int v = 0; v < 4; ++v) Of[of][v] *= alpha[v];

        // P -> LDS (bf16), wave-private
        #pragma unroll
        for (int nf = 0; nf < 4; ++nf)
            #pragma unroll
            for (int v = 0; v < 4; ++v)
                Pl[w][kb * 4 + v][nf * 16 + r16] = f2bf(Sf[nf][v]);
        asm volatile("s_waitcnt lgkmcnt(0)" ::: "memory");

        // O += P V
        #pragma unroll
        for (int ka = 0; ka < 2; ++ka) {
            short8v pf = __builtin_bit_cast(short8v,
                *(const ushort8v*)&Pl[w][r16][ka * 32 + kb * 8]);
            #pragma unroll
            for (int of = 0; of < 8; ++of) {
                short8v vf = __builtin_bit_cast(short8v,
                    *(const ushort8v*)&Vt[of * 16 + r16][ka * 32 + kb * 8]);
                Of[of] = __builtin_amdgcn_mfma_f32_16x16x32_bf16(pf, vf, Of[of], 0, 0, 0);
            }
        }
    }

    float invl[4];
    #pragma unroll
    for (int v = 0; v < 4; ++v) invl[v] = 1.0f / l_i[v];
    #pragma unroll
    for (int of = 0; of < 8; ++of)
        #pragma unroll
        for (int v = 0; v < 4; ++v) {
            int qrow = qt * 64 + w * 16 + kb * 4 + v;
            int d = of * 16 + r16;
            yout[(size_t)(b * 512 + qrow) * 2048 + h * 128 + d] = Of[of][v] * invl[v];
        }
}

// ---------------------------------------------------------------------------
// Kernel 4: quantize new K/V rows (window rows 3584..4095). 1 wave/row.
// ---------------------------------------------------------------------------
__global__ __launch_bounds__(256) void quant_new_kernel(
    const float* __restrict__ kn, const float* __restrict__ vn,
    float* __restrict__ oktq, float* __restrict__ ovtq,
    float* __restrict__ oksc, float* __restrict__ ovsc) {
    const int row  = blockIdx.x * 4 + (threadIdx.x >> 6);  // 0..32767
    const int lane = threadIdx.x & 63;
    const int bh = row >> 9, i = row & 511;
    f32x2 kv = *(const f32x2*)(kn + (size_t)row * 128 + lane * 2);
    f32x2 vv = *(const f32x2*)(vn + (size_t)row * 128 + lane * 2);
    float kam = fmaxf(fabsf(kv[0]), fabsf(kv[1]));
    float vam = fmaxf(fabsf(vv[0]), fabsf(vv[1]));
    #pragma unroll
    for (int off = 1; off < 64; off <<= 1) {
        kam = fmaxf(kam, __shfl_xor(kam, off, 64));
        vam = fmaxf(vam, __shfl_xor(vam, off, 64));
    }
    float kscale = fmaxf(kam / 127.0f, 1e-8f);
    float vscale = fmaxf(vam / 127.0f, 1e-8f);
    float kinv = 1.0f / kscale, vinv = 1.0f / vscale;
    const size_t orow = (size_t)bh * 4096 + 3584 + i;
    f32x2 ko, vo;
    ko[0] = fminf(fmaxf(rintf(kv[0] * kinv), -127.f), 127.f);
    ko[1] = fminf(fmaxf(rintf(kv[1] * kinv), -127.f), 127.f);
    vo[0] = fminf(fmaxf(rintf(vv[0] * vinv), -127.f), 127.f);
    vo[1] = fminf(fmaxf(rintf(vv[1] * vinv), -127.f), 127.f);
    *(f32x2*)(oktq + orow * 128 + lane * 2) = ko;
    *(f32x2*)(ovtq + orow * 128 + lane * 2) = vo;
    if (lane == 0) {
        oksc[orow] = __half2float(__float2half(kscale));
        ovsc[orow] = __half2float(__float2half(vscale));
    }
}

// ---------------------------------------------------------------------------
extern "C" void kernel_launch(void* const* d_in, const int* in_sizes, int n_in,
                              void* d_out, int out_size, void* d_ws, size_t ws_size,
                              hipStream_t stream) {
    (void)in_sizes; (void)n_in; (void)out_size; (void)ws_size;
    const float* x   = (const float*)d_in[0];
    const int*   kq  = (const int*)d_in[1];
    const int*   vq  = (const int*)d_in[2];
    const float* ks  = (const float*)d_in[3];
    const float* vs  = (const float*)d_in[4];
    const float* Wq  = (const float*)d_in[5];
    const float* Wk  = (const float*)d_in[6];
    const float* Wv  = (const float*)d_in[7];
    const float* Wo  = (const float*)d_in[8];

    float* out  = (float*)d_out;
    float* y_o  = out;
    float* oktq = out + 4194304;     // 4*512*2048
    float* ovtq = out + 37748736;    // + 4*16*4096*128
    float* oksc = out + 71303168;
    float* ovsc = out + 71565312;

    char* wsb = (char*)d_ws;
    float*        q_ws  = (float*)(wsb);                               // 16 MB
    unsigned int* kc_ws = (unsigned int*)(wsb + 16777216);             // 64 MB
    unsigned int* vc_ws = (unsigned int*)(wsb + 16777216 + 67108864);  // 64 MB
    float*        kn_ws = (float*)(wsb + 16777216 + 2*67108864);       // 16 MB
    float*        vn_ws = (float*)(wsb + 2*16777216 + 2*67108864);     // 16 MB
    float*        ya_ws = (float*)(wsb + 3*16777216 + 2*67108864);     // 16 MB

    prep_cache_kernel<<<65536, 256, 0, stream>>>(kq, vq, ks, vs, kc_ws, vc_ws,
                                                 oktq, ovtq, oksc, ovsc);
    gemm_bt_kernel<0><<<256, 256, 0, stream>>>(x, Wq, q_ws);
    gemm_bt_kernel<0><<<256, 256, 0, stream>>>(x, Wk, kn_ws);
    gemm_bt_kernel<0><<<256, 256, 0, stream>>>(x, Wv, vn_ws);
    quant_new_kernel<<<8192, 256, 0, stream>>>(kn_ws, vn_ws, oktq, ovtq, oksc, ovsc);
    attn_kernel<<<512, 256, 0, stream>>>(q_ws,
                                         (const unsigned short*)kc_ws,
                                         (const unsigned short*)vc_ws,
                                         kn_ws, vn_ws, ya_ws);
    gemm_bt_kernel<1><<<256, 256, 0, stream>>>(ya_ws, Wo, y_o);
}

// Round 2
// 780.646 us; speedup vs baseline: 1.2303x; 1.2303x over previous
//
#include <hip/hip_runtime.h>
#include <hip/hip_fp16.h>

typedef float   f32x4   __attribute__((ext_vector_type(4)));
typedef float   f32x2   __attribute__((ext_vector_type(2)));
typedef short   short8v __attribute__((ext_vector_type(8)));
typedef unsigned short ushort8v __attribute__((ext_vector_type(8)));
typedef int     int2v   __attribute__((ext_vector_type(2)));

#define DEVI static __device__ __forceinline__

DEVI unsigned short f2bf(float f) {
    unsigned int u = __builtin_bit_cast(unsigned int, f);
    u += 0x7FFFu + ((u >> 16) & 1u);   // RNE (inputs finite)
    return (unsigned short)(u >> 16);
}

// ---------------------------------------------------------------------------
// Kernel 1: per (bh, 64-key tile): dequant cache -> bf16 K rows (packed u32)
// + bf16 V^T columns (transpose via LDS), exact requant of window rows.
// Grid 4096 = 64 bh * 64 tiles, 256 threads.
// ---------------------------------------------------------------------------
__global__ __launch_bounds__(256) void prep_cache_kernel(
    const int* __restrict__ kq, const int* __restrict__ vq,
    const float* __restrict__ ks, const float* __restrict__ vs,
    unsigned int* __restrict__ kcp, unsigned short* __restrict__ vt,
    float* __restrict__ oktq, float* __restrict__ ovtq,
    float* __restrict__ oksc, float* __restrict__ ovsc) {
    __shared__ unsigned short Vs[64][132];
    __shared__ float skL[64], svL[64];
    const int tid = threadIdx.x;
    const int bh = blockIdx.x >> 6, kt = blockIdx.x & 63;
    const int key0 = kt << 6;
    const size_t rowbase = (size_t)bh * 4096 + key0;
    if (tid < 64) { skL[tid] = ks[rowbase + tid]; svL[tid] = vs[rowbase + tid]; }
    __syncthreads();
    const int lane = tid & 63, w = tid >> 6;
    #pragma unroll 4
    for (int s = 0; s < 16; ++s) {
        const int key = s * 4 + w;
        const size_t row = rowbase + key;
        const float sk = skL[key], sv = svL[key];
        int2v kv = *(const int2v*)(kq + row * 128 + lane * 2);
        int2v vv = *(const int2v*)(vq + row * 128 + lane * 2);
        float kx0 = (float)kv[0] * sk, kx1 = (float)kv[1] * sk;
        float vx0 = (float)vv[0] * sv, vx1 = (float)vv[1] * sv;
        kcp[row * 64 + lane] = (unsigned)f2bf(kx0) | ((unsigned)f2bf(kx1) << 16);
        *(unsigned int*)&Vs[key][lane * 2] =
            (unsigned)f2bf(vx0) | ((unsigned)f2bf(vx1) << 16);
        float kam = fmaxf(fabsf(kx0), fabsf(kx1));
        float vam = fmaxf(fabsf(vx0), fabsf(vx1));
        #pragma unroll
        for (int off = 1; off < 64; off <<= 1) {
            kam = fmaxf(kam, __shfl_xor(kam, off, 64));
            vam = fmaxf(vam, __shfl_xor(vam, off, 64));
        }
        const int r = key0 + key;
        if (r >= 512) {
            const size_t orow = (size_t)bh * 4096 + (size_t)(r - 512);
            float kscale = fmaxf(kam / 127.0f, 1e-8f);
            float vscale = fmaxf(vam / 127.0f, 1e-8f);
            float kinv = 1.0f / kscale, vinv = 1.0f / vscale;
            f32x2 ko, vo;
            ko[0] = fminf(fmaxf(rintf(kx0 * kinv), -127.f), 127.f);
            ko[1] = fminf(fmaxf(rintf(kx1 * kinv), -127.f), 127.f);
            vo[0] = fminf(fmaxf(rintf(vx0 * vinv), -127.f), 127.f);
            vo[1] = fminf(fmaxf(rintf(vx1 * vinv), -127.f), 127.f);
            *(f32x2*)(oktq + orow * 128 + lane * 2) = ko;
            *(f32x2*)(ovtq + orow * 128 + lane * 2) = vo;
            if (lane == 0) {
                oksc[orow] = __half2float(__float2half(kscale));
                ovsc[orow] = __half2float(__float2half(vscale));
            }
        }
    }
    __syncthreads();
    // transposed write-out: V^T[d][key0..key0+63]
    const int d = tid >> 1, half = tid & 1;
    unsigned short* obase = vt + ((size_t)bh * 128 + d) * 4608 + key0 + half * 32;
    #pragma unroll
    for (int c = 0; c < 4; ++c) {
        ushort8v tv;
        #pragma unroll
        for (int e = 0; e < 8; ++e) tv[e] = Vs[half * 32 + c * 8 + e][d];
        *(ushort8v*)(obase + c * 8) = tv;
    }
}

// ---------------------------------------------------------------------------
// Kernel 2: GEMM  C[m][n] = sum_k A[m][k] * W[n][k]   (M=N=K=2048)
// MODE 0: write head-split ((b*16+h)*512+i)*128+d ; MODE 1: plain row-major.
// ---------------------------------------------------------------------------
template <int MODE>
__global__ __launch_bounds__(256) void gemm_bt_kernel(
    const float* __restrict__ A, const float* __restrict__ Bw,
    float* __restrict__ C) {
    __shared__ unsigned short As[128][40];
    __shared__ unsigned short Bs[128][40];
    const int tid  = threadIdx.x;
    const int bm   = blockIdx.x & 15, bn = blockIdx.x >> 4;
    const int m0   = bm * 128, n0 = bn * 128;
    const int lane = tid & 63, w = tid >> 6;
    const int wm   = (w >> 1) * 64, wn = (w & 1) * 64;
    const int r16  = lane & 15, kb = lane >> 4;

    f32x4 acc[4][4] = {};

    for (int k0 = 0; k0 < 2048; k0 += 32) {
        __syncthreads();
        #pragma unroll
        for (int s = 0; s < 4; ++s) {
            int flat = tid + s * 256;
            int row = flat >> 3, col = (flat & 7) << 2;
            f32x4 av = *(const f32x4*)(A  + (size_t)(m0 + row) * 2048 + k0 + col);
            f32x4 bv = *(const f32x4*)(Bw + (size_t)(n0 + row) * 2048 + k0 + col);
            As[row][col+0]=f2bf(av[0]); As[row][col+1]=f2bf(av[1]);
            As[row][col+2]=f2bf(av[2]); As[row][col+3]=f2bf(av[3]);
            Bs[row][col+0]=f2bf(bv[0]); Bs[row][col+1]=f2bf(bv[1]);
            Bs[row][col+2]=f2bf(bv[2]); Bs[row][col+3]=f2bf(bv[3]);
        }
        __syncthreads();
        short8v af[4], bf[4];
        #pragma unroll
        for (int mf = 0; mf < 4; ++mf)
            af[mf] = __builtin_bit_cast(short8v, *(const ushort8v*)&As[wm + mf*16 + r16][kb*8]);
        #pragma unroll
        for (int nf = 0; nf < 4; ++nf)
            bf[nf] = __builtin_bit_cast(short8v, *(const ushort8v*)&Bs[wn + nf*16 + r16][kb*8]);
        #pragma unroll
        for (int mf = 0; mf < 4; ++mf)
            #pragma unroll
            for (int nf = 0; nf < 4; ++nf)
                acc[mf][nf] = __builtin_amdgcn_mfma_f32_16x16x32_bf16(af[mf], bf[nf], acc[mf][nf], 0, 0, 0);
    }

    #pragma unroll
    for (int mf = 0; mf < 4; ++mf)
        #pragma unroll
        for (int nf = 0; nf < 4; ++nf)
            #pragma unroll
            for (int v = 0; v < 4; ++v) {
                int mg = m0 + wm + mf * 16 + kb * 4 + v;
                int ng = n0 + wn + nf * 16 + r16;
                float val = acc[mf][nf][v];
                if (MODE == 0) {
                    int b = mg >> 9, i = mg & 511, h = ng >> 7, d = ng & 127;
                    C[(((size_t)b * 16 + h) * 512 + i) * 128 + d] = val;
                } else {
                    C[(size_t)mg * 2048 + ng] = val;
                }
            }
}

// ---------------------------------------------------------------------------
// Kernel 3: quantize new K/V rows + produce V^T bf16 cols 4096..4607.
// Grid 512 = 64 bh * 8 tiles, 256 threads.
// ---------------------------------------------------------------------------
__global__ __launch_bounds__(256) void quant_new_kernel(
    const float* __restrict__ kn, const float* __restrict__ vn,
    unsigned short* __restrict__ vt,
    float* __restrict__ oktq, float* __restrict__ ovtq,
    float* __restrict__ oksc, float* __restrict__ ovsc) {
    __shared__ unsigned short Vs[64][132];
    const int tid = threadIdx.x;
    const int bh = blockIdx.x >> 3, kt = blockIdx.x & 7;
    const int i0 = kt << 6;
    const int lane = tid & 63, w = tid >> 6;
    #pragma unroll 4
    for (int s = 0; s < 16; ++s) {
        const int key = s * 4 + w;
        const int i = i0 + key;
        const size_t row = (size_t)bh * 512 + i;
        f32x2 kv = *(const f32x2*)(kn + row * 128 + lane * 2);
        f32x2 vv = *(const f32x2*)(vn + row * 128 + lane * 2);
        *(unsigned int*)&Vs[key][lane * 2] =
            (unsigned)f2bf(vv[0]) | ((unsigned)f2bf(vv[1]) << 16);
        float kam = fmaxf(fabsf(kv[0]), fabsf(kv[1]));
        float vam = fmaxf(fabsf(vv[0]), fabsf(vv[1]));
        #pragma unroll
        for (int off = 1; off < 64; off <<= 1) {
            kam = fmaxf(kam, __shfl_xor(kam, off, 64));
            vam = fmaxf(vam, __shfl_xor(vam, off, 64));
        }
        float kscale = fmaxf(kam / 127.0f, 1e-8f);
        float vscale = fmaxf(vam / 127.0f, 1e-8f);
        float kinv = 1.0f / kscale, vinv = 1.0f / vscale;
        const size_t orow = (size_t)bh * 4096 + 3584 + i;
        f32x2 ko, vo;
        ko[0] = fminf(fmaxf(rintf(kv[0] * kinv), -127.f), 127.f);
        ko[1] = fminf(fmaxf(rintf(kv[1] * kinv), -127.f), 127.f);
        vo[0] = fminf(fmaxf(rintf(vv[0] * vinv), -127.f), 127.f);
        vo[1] = fminf(fmaxf(rintf(vv[1] * vinv), -127.f), 127.f);
        *(f32x2*)(oktq + orow * 128 + lane * 2) = ko;
        *(f32x2*)(ovtq + orow * 128 + lane * 2) = vo;
        if (lane == 0) {
            oksc[orow] = __half2float(__float2half(kscale));
            ovsc[orow] = __half2float(__float2half(vscale));
        }
    }
    __syncthreads();
    const int d = tid >> 1, half = tid & 1;
    unsigned short* obase = vt + ((size_t)bh * 128 + d) * 4608 + 4096 + i0 + half * 32;
    #pragma unroll
    for (int c = 0; c < 4; ++c) {
        ushort8v tv;
        #pragma unroll
        for (int e = 0; e < 8; ++e) tv[e] = Vs[half * 32 + c * 8 + e][d];
        *(ushort8v*)(obase + c * 8) = tv;
    }
}

// ---------------------------------------------------------------------------
// Kernel 4: flash attention. 256 blocks = (b,h) x 4 q-tiles of 128 rows.
// 8 waves/block, 16 query rows/wave. 64-key tiles; V from global V^T (bf16).
// XCD-bijective swizzle: all q-tiles of one bh land on one XCD.
// ---------------------------------------------------------------------------
__global__ __launch_bounds__(512) void attn_kernel(
    const float* __restrict__ qw,
    const unsigned short* __restrict__ kc,
    const float* __restrict__ kn,
    const unsigned short* __restrict__ vt,
    float* __restrict__ yout) {
    __shared__ unsigned short Ks[64][136];   // [key][d]
    __shared__ unsigned short Vl[128][72];   // [d][key]
    __shared__ unsigned short Pl[8][16][72]; // per-wave P round-trip

    const int tid = threadIdx.x, lane = tid & 63, w = tid >> 6;
    const int p = blockIdx.x;
    const int bh = ((p >> 5) << 3) + (p & 7);   // p%8 == bh%8 -> same XCD per bh
    const int qt = (p >> 3) & 3;
    const int b = bh >> 4, h = bh & 15;
    const int r16 = lane & 15, kb = lane >> 4;
    const float rscale = 0.08838834764831845f;  // 1/sqrt(128)

    const int qrow_frag = qt * 128 + w * 16 + r16;
    const float* qp = qw + ((size_t)bh * 512 + qrow_frag) * 128;
    short8v qf[4];
    #pragma unroll
    for (int f = 0; f < 4; ++f) {
        ushort8v t;
        #pragma unroll
        for (int e = 0; e < 8; ++e) t[e] = f2bf(qp[f * 32 + kb * 8 + e] * rscale);
        qf[f] = __builtin_bit_cast(short8v, t);
    }

    f32x4 Of[8] = {};
    float m_i[4], l_i[4];
    #pragma unroll
    for (int v = 0; v < 4; ++v) { m_i[v] = -3.0e38f; l_i[v] = 0.f; }

    const unsigned short* vbase = vt + (size_t)bh * 128 * 4608;
    const int ntiles = 66 + qt * 2;
    for (int kt = 0; kt < ntiles; ++kt) {
        __syncthreads();
        if (kt < 64) {
            const unsigned short* ksrc = kc + ((size_t)bh * 4096 + kt * 64) * 128;
            #pragma unroll
            for (int s = 0; s < 2; ++s) {
                int flat = tid + s * 512;
                int row = flat >> 4, c8 = (flat & 15) << 3;
                *(ushort8v*)&Ks[row][c8] = *(const ushort8v*)(ksrc + row * 128 + c8);
            }
        } else {
            const float* ksrc = kn + ((size_t)bh * 512 + (kt - 64) * 64) * 128;
            #pragma unroll
            for (int s = 0; s < 2; ++s) {
                int flat = tid + s * 512;
                int row = flat >> 4, c8 = (flat & 15) << 3;
                const float* kp = ksrc + row * 128 + c8;
                f32x4 k0 = *(const f32x4*)kp, k1 = *(const f32x4*)(kp + 4);
                ushort8v t;
                t[0]=f2bf(k0[0]); t[1]=f2bf(k0[1]); t[2]=f2bf(k0[2]); t[3]=f2bf(k0[3]);
                t[4]=f2bf(k1[0]); t[5]=f2bf(k1[1]); t[6]=f2bf(k1[2]); t[7]=f2bf(k1[3]);
                *(ushort8v*)&Ks[row][c8] = t;
            }
        }
        {
            const unsigned short* vsrc = vbase + kt * 64;
            #pragma unroll
            for (int s = 0; s < 2; ++s) {
                int flat = tid + s * 512;
                int d = flat >> 3, c8 = (flat & 7) << 3;
                *(ushort8v*)&Vl[d][c8] = *(const ushort8v*)(vsrc + (size_t)d * 4608 + c8);
            }
        }
        __syncthreads();

        // S = (Q*scale) K^T : 16 x 64 per wave
        f32x4 Sf[4] = {};
        __builtin_amdgcn_s_setprio(1);
        #pragma unroll
        for (int nf = 0; nf < 4; ++nf)
            #pragma unroll
            for (int ks = 0; ks < 4; ++ks) {
                short8v kf = __builtin_bit_cast(short8v,
                    *(const ushort8v*)&Ks[nf * 16 + r16][ks * 32 + kb * 8]);
                Sf[nf] = __builtin_amdgcn_mfma_f32_16x16x32_bf16(qf[ks], kf, Sf[nf], 0, 0, 0);
            }
        __builtin_amdgcn_s_setprio(0);

        if (kt >= 64) {  // causal mask within the new segment
            const int jn0 = (kt - 64) * 64;
            const int qbase = qt * 128 + w * 16;
            #pragma unroll
            for (int nf = 0; nf < 4; ++nf) {
                int jn = jn0 + nf * 16 + r16;
                #pragma unroll
                for (int v = 0; v < 4; ++v)
                    if (jn > qbase + kb * 4 + v) Sf[nf][v] = -3.0e38f;
            }
        }

        // online softmax (row q=kb*4+v lives across the 16 r16 lanes)
        float alpha[4], rsum[4];
        #pragma unroll
        for (int v = 0; v < 4; ++v) {
            float mx = fmaxf(fmaxf(Sf[0][v], Sf[1][v]), fmaxf(Sf[2][v], Sf[3][v]));
            #pragma unroll
            for (int off = 1; off < 16; off <<= 1) mx = fmaxf(mx, __shfl_xor(mx, off, 64));
            float mnew = fmaxf(m_i[v], mx);
            alpha[v] = __expf(m_i[v] - mnew);
            m_i[v] = mnew;
            rsum[v] = 0.f;
        }
        #pragma unroll
        for (int nf = 0; nf < 4; ++nf)
            #pragma unroll
            for (int v = 0; v < 4; ++v) {
                float pq = __expf(Sf[nf][v] - m_i[v]);
                Sf[nf][v] = pq;
                rsum[v] += pq;
            }
        #pragma unroll
        for (int v = 0; v < 4; ++v) {
            float sm = rsum[v];
            #pragma unroll
            for (int off = 1; off < 16; off <<= 1) sm += __shfl_xor(sm, off, 64);
            l_i[v] = l_i[v] * alpha[v] + sm;
        }
        #pragma unroll
        for (int of = 0; of < 8; ++of)
            #pragma unroll
            for (int v = 0; v < 4; ++v) Of[of][v] *= alpha[v];

        // P -> LDS (bf16), wave-private
        #pragma unroll
        for (int nf = 0; nf < 4; ++nf)
            #pragma unroll
            for (int v = 0; v < 4; ++v)
                Pl[w][kb * 4 + v][nf * 16 + r16] = f2bf(Sf[nf][v]);
        asm volatile("s_waitcnt lgkmcnt(0)" ::: "memory");

        // O += P V
        __builtin_amdgcn_s_setprio(1);
        #pragma unroll
        for (int ka = 0; ka < 2; ++ka) {
            short8v pf = __builtin_bit_cast(short8v,
                *(const ushort8v*)&Pl[w][r16][ka * 32 + kb * 8]);
            #pragma unroll
            for (int of = 0; of < 8; ++of) {
                short8v vf = __builtin_bit_cast(short8v,
                    *(const ushort8v*)&Vl[of * 16 + r16][ka * 32 + kb * 8]);
                Of[of] = __builtin_amdgcn_mfma_f32_16x16x32_bf16(pf, vf, Of[of], 0, 0, 0);
            }
        }
        __builtin_amdgcn_s_setprio(0);
    }

    float invl[4];
    #pragma unroll
    for (int v = 0; v < 4; ++v) invl[v] = 1.0f / l_i[v];
    #pragma unroll
    for (int of = 0; of < 8; ++of)
        #pragma unroll
        for (int v = 0; v < 4; ++v) {
            int qrow = qt * 128 + w * 16 + kb * 4 + v;
            int d = of * 16 + r16;
            yout[(size_t)(b * 512 + qrow) * 2048 + h * 128 + d] = Of[of][v] * invl[v];
        }
}

// ---------------------------------------------------------------------------
extern "C" void kernel_launch(void* const* d_in, const int* in_sizes, int n_in,
                              void* d_out, int out_size, void* d_ws, size_t ws_size,
                              hipStream_t stream) {
    (void)in_sizes; (void)n_in; (void)out_size; (void)ws_size;
    const float* x   = (const float*)d_in[0];
    const int*   kq  = (const int*)d_in[1];
    const int*   vq  = (const int*)d_in[2];
    const float* ks  = (const float*)d_in[3];
    const float* vs  = (const float*)d_in[4];
    const float* Wq  = (const float*)d_in[5];
    const float* Wk  = (const float*)d_in[6];
    const float* Wv  = (const float*)d_in[7];
    const float* Wo  = (const float*)d_in[8];

    float* out  = (float*)d_out;
    float* y_o  = out;
    float* oktq = out + 4194304;
    float* ovtq = out + 37748736;
    float* oksc = out + 71303168;
    float* ovsc = out + 71565312;

    char* wsb = (char*)d_ws;
    float*          q_ws  = (float*)(wsb);                                // 16 MB @ 0
    unsigned int*   kc_ws = (unsigned int*)(wsb + (16u << 20));           // 64 MB @ 16 MB
    unsigned short* vt_ws = (unsigned short*)(wsb + (80u << 20));         // 72 MB @ 80 MB
    float*          kn_ws = (float*)(wsb + (160u << 20));                 // 16 MB @ 160 MB
    float*          vn_ws = (float*)(wsb + (176u << 20));                 // 16 MB @ 176 MB
    float*          ya_ws = vn_ws;  // vn dead after quant_new; attn reads V from vt_ws

    prep_cache_kernel<<<4096, 256, 0, stream>>>(kq, vq, ks, vs, kc_ws, vt_ws,
                                                oktq, ovtq, oksc, ovsc);
    gemm_bt_kernel<0><<<256, 256, 0, stream>>>(x, Wq, q_ws);
    gemm_bt_kernel<0><<<256, 256, 0, stream>>>(x, Wk, kn_ws);
    gemm_bt_kernel<0><<<256, 256, 0, stream>>>(x, Wv, vn_ws);
    quant_new_kernel<<<512, 256, 0, stream>>>(kn_ws, vn_ws, vt_ws,
                                              oktq, ovtq, oksc, ovsc);
    attn_kernel<<<256, 512, 0, stream>>>(q_ws,
                                         (const unsigned short*)kc_ws,
                                         kn_ws, vt_ws, ya_ws);
    gemm_bt_kernel<1><<<256, 256, 0, stream>>>(ya_ws, Wo, y_o);
}

// Round 3
// 549.186 us; speedup vs baseline: 1.7488x; 1.4215x over previous
//
#include <hip/hip_runtime.h>
#include <hip/hip_fp16.h>

typedef float   f32x4   __attribute__((ext_vector_type(4)));
typedef float   f32x2   __attribute__((ext_vector_type(2)));
typedef short   short8v __attribute__((ext_vector_type(8)));
typedef unsigned short ushort8v __attribute__((ext_vector_type(8)));
typedef int     int2v   __attribute__((ext_vector_type(2)));
typedef unsigned int   u32;
typedef unsigned short u16;

#define DEVI static __device__ __forceinline__

DEVI u16 f2bf(float f) {
    u32 u = __builtin_bit_cast(u32, f);
    u += 0x7FFFu + ((u >> 16) & 1u);   // RNE (inputs finite)
    return (u16)(u >> 16);
}
DEVI float bf2f(u16 h) { return __builtin_bit_cast(float, (u32)h << 16); }

// async global->LDS, 16B per lane; lds ptr must be wave-uniform (lane*16 added by HW)
DEVI void gl_lds16(const u16* g, u16* l) {
    __builtin_amdgcn_global_load_lds(
        (const __attribute__((address_space(1))) u32*)(const void*)g,
        (__attribute__((address_space(3))) u32*)(void*)l, 16, 0, 0);
}

// ---------------------------------------------------------------------------
// convert f32 -> bf16 (optionally scaled). n8 = elements/8.
// ---------------------------------------------------------------------------
__global__ __launch_bounds__(256) void convert_kernel(
    const float* __restrict__ src, u16* __restrict__ dst, float scale, int n8) {
    int idx = blockIdx.x * 256 + threadIdx.x;
    if (idx >= n8) return;
    const float* p = src + (size_t)idx * 8;
    f32x4 a = *(const f32x4*)p, b = *(const f32x4*)(p + 4);
    ushort8v o;
    o[0]=f2bf(a[0]*scale); o[1]=f2bf(a[1]*scale); o[2]=f2bf(a[2]*scale); o[3]=f2bf(a[3]*scale);
    o[4]=f2bf(b[0]*scale); o[5]=f2bf(b[1]*scale); o[6]=f2bf(b[2]*scale); o[7]=f2bf(b[3]*scale);
    *(ushort8v*)(dst + (size_t)idx * 8) = o;
}

// ---------------------------------------------------------------------------
// prep_cache: dequant cache -> bf16 K rows (into kcb rows 0..4095) + bf16 V^T
// cols 0..4095 (transpose via LDS) + exact requant of window rows 512..4095.
// Grid 4096 = 64 bh * 64 tiles, 256 threads.
// ---------------------------------------------------------------------------
__global__ __launch_bounds__(256) void prep_cache_kernel(
    const int* __restrict__ kq, const int* __restrict__ vq,
    const float* __restrict__ ks, const float* __restrict__ vs,
    u16* __restrict__ kcb, u16* __restrict__ vt,
    float* __restrict__ oktq, float* __restrict__ ovtq,
    float* __restrict__ oksc, float* __restrict__ ovsc) {
    __shared__ u16 Vs[64][132];
    __shared__ float skL[64], svL[64];
    const int tid = threadIdx.x;
    const int bh = blockIdx.x >> 6, kt = blockIdx.x & 63;
    const int key0 = kt << 6;
    const size_t rowbase = (size_t)bh * 4096 + key0;
    if (tid < 64) { skL[tid] = ks[rowbase + tid]; svL[tid] = vs[rowbase + tid]; }
    __syncthreads();
    const int lane = tid & 63, w = tid >> 6;
    u32* kcw = (u32*)kcb;
    #pragma unroll 4
    for (int s = 0; s < 16; ++s) {
        const int key = s * 4 + w;
        const size_t row = rowbase + key;
        const float sk = skL[key], sv = svL[key];
        int2v kv = *(const int2v*)(kq + row * 128 + lane * 2);
        int2v vv = *(const int2v*)(vq + row * 128 + lane * 2);
        float kx0 = (float)kv[0] * sk, kx1 = (float)kv[1] * sk;
        float vx0 = (float)vv[0] * sv, vx1 = (float)vv[1] * sv;
        kcw[(size_t)(bh * 4608 + key0 + key) * 64 + lane] =
            (u32)f2bf(kx0) | ((u32)f2bf(kx1) << 16);
        *(u32*)&Vs[key][lane * 2] = (u32)f2bf(vx0) | ((u32)f2bf(vx1) << 16);
        float kam = fmaxf(fabsf(kx0), fabsf(kx1));
        float vam = fmaxf(fabsf(vx0), fabsf(vx1));
        #pragma unroll
        for (int off = 1; off < 64; off <<= 1) {
            kam = fmaxf(kam, __shfl_xor(kam, off, 64));
            vam = fmaxf(vam, __shfl_xor(vam, off, 64));
        }
        const int r = key0 + key;
        if (r >= 512) {
            const size_t orow = (size_t)bh * 4096 + (size_t)(r - 512);
            float kscale = fmaxf(kam / 127.0f, 1e-8f);
            float vscale = fmaxf(vam / 127.0f, 1e-8f);
            float kinv = 1.0f / kscale, vinv = 1.0f / vscale;
            f32x2 ko, vo;
            ko[0] = fminf(fmaxf(rintf(kx0 * kinv), -127.f), 127.f);
            ko[1] = fminf(fmaxf(rintf(kx1 * kinv), -127.f), 127.f);
            vo[0] = fminf(fmaxf(rintf(vx0 * vinv), -127.f), 127.f);
            vo[1] = fminf(fmaxf(rintf(vx1 * vinv), -127.f), 127.f);
            *(f32x2*)(oktq + orow * 128 + lane * 2) = ko;
            *(f32x2*)(ovtq + orow * 128 + lane * 2) = vo;
            if (lane == 0) {
                oksc[orow] = __half2float(__float2half(kscale));
                ovsc[orow] = __half2float(__float2half(vscale));
            }
        }
    }
    __syncthreads();
    const int d = tid >> 1, half = tid & 1;
    u16* obase = vt + ((size_t)bh * 128 + d) * 4608 + key0 + half * 32;
    #pragma unroll
    for (int c = 0; c < 4; ++c) {
        ushort8v tv;
        #pragma unroll
        for (int e = 0; e < 8; ++e) tv[e] = Vs[half * 32 + c * 8 + e][d];
        *(ushort8v*)(obase + c * 8) = tv;
    }
}

// ---------------------------------------------------------------------------
// bf16 GEMM  C[m][n] = sum_k A[m][k] * B[n][k]  (2048^3), BM=128 BN=64 BK=64,
// 256 thr (4 waves 2x2 of 64x32), gload_lds + XOR-swizzle + 2-phase dbuf.
// MODE 0: q bf16 head-split; 1: kcb bf16 rows 4096..; 2: vnb bf16 head-split;
// 3: f32 row-major.
// ---------------------------------------------------------------------------
template <int MODE>
__global__ __launch_bounds__(256) void gemm_bf16_kernel(
    const u16* __restrict__ A, const u16* __restrict__ Bw,
    void* __restrict__ Cout) {
    __shared__ u16 As[2][128 * 64];
    __shared__ u16 Bs[2][64 * 64];
    const int tid = threadIdx.x, lane = tid & 63, w = tid >> 6;
    const int sid = (blockIdx.x & 7) * 64 + (blockIdx.x >> 3);  // XCD-chunked
    const int bm = sid & 15, bn = sid >> 4;
    const int m0 = bm * 128, n0 = bn * 64;
    const int wm = (w >> 1) * 64, wn = (w & 1) * 32;
    const int r16 = lane & 15, kb = lane >> 4;

    f32x4 acc[4][2] = {};

    auto stage = [&](int bi, int k0) {
        #pragma unroll
        for (int i = 0; i < 4; ++i) {
            int s = i * 256 + tid;
            int row = s >> 3, l = (s & 7) ^ (row & 7);
            gl_lds16(A + (size_t)(m0 + row) * 2048 + k0 + l * 8,
                     &As[bi][(i * 256 + (tid & ~63)) * 8]);
        }
        #pragma unroll
        for (int i = 0; i < 2; ++i) {
            int s = i * 256 + tid;
            int row = s >> 3, l = (s & 7) ^ (row & 7);
            gl_lds16(Bw + (size_t)(n0 + row) * 2048 + k0 + l * 8,
                     &Bs[bi][(i * 256 + (tid & ~63)) * 8]);
        }
    };

    stage(0, 0);
    __syncthreads();
    int cur = 0;
    for (int t = 0; t < 32; ++t) {
        if (t < 31) stage(cur ^ 1, (t + 1) * 64);
        short8v af[4][2], bf[2][2];
        #pragma unroll
        for (int mf = 0; mf < 4; ++mf) {
            int row = wm + mf * 16 + r16;
            #pragma unroll
            for (int ksv = 0; ksv < 2; ++ksv) {
                int blk = (ksv * 4 + kb) ^ (row & 7);
                af[mf][ksv] = __builtin_bit_cast(short8v,
                    *(const ushort8v*)&As[cur][row * 64 + blk * 8]);
            }
        }
        #pragma unroll
        for (int nf = 0; nf < 2; ++nf) {
            int row = wn + nf * 16 + r16;
            #pragma unroll
            for (int ksv = 0; ksv < 2; ++ksv) {
                int blk = (ksv * 4 + kb) ^ (row & 7);
                bf[nf][ksv] = __builtin_bit_cast(short8v,
                    *(const ushort8v*)&Bs[cur][row * 64 + blk * 8]);
            }
        }
        #pragma unroll
        for (int mf = 0; mf < 4; ++mf)
            #pragma unroll
            for (int nf = 0; nf < 2; ++nf)
                #pragma unroll
                for (int ksv = 0; ksv < 2; ++ksv)
                    acc[mf][nf] = __builtin_amdgcn_mfma_f32_16x16x32_bf16(
                        af[mf][ksv], bf[nf][ksv], acc[mf][nf], 0, 0, 0);
        __syncthreads();
        cur ^= 1;
    }

    #pragma unroll
    for (int mf = 0; mf < 4; ++mf)
        #pragma unroll
        for (int nf = 0; nf < 2; ++nf)
            #pragma unroll
            for (int v = 0; v < 4; ++v) {
                int mg = m0 + wm + mf * 16 + kb * 4 + v;
                int ng = n0 + wn + nf * 16 + r16;
                float val = acc[mf][nf][v];
                if (MODE == 0 || MODE == 2) {
                    ((u16*)Cout)[(((size_t)(mg >> 9) * 16 + (ng >> 7)) * 512 +
                                  (mg & 511)) * 128 + (ng & 127)] = f2bf(val);
                } else if (MODE == 1) {
                    size_t bh = (size_t)(mg >> 9) * 16 + (ng >> 7);
                    ((u16*)Cout)[(bh * 4608 + 4096 + (mg & 511)) * 128 + (ng & 127)] = f2bf(val);
                } else {
                    ((float*)Cout)[(size_t)mg * 2048 + ng] = val;
                }
            }
}

// ---------------------------------------------------------------------------
// quant_new: quantize new K/V rows (from bf16 kcb rows 4096.., vnb) + V^T
// cols 4096..4607. Grid 512 = 64 bh * 8 tiles, 256 threads.
// ---------------------------------------------------------------------------
__global__ __launch_bounds__(256) void quant_new_kernel(
    const u16* __restrict__ kcb, const u16* __restrict__ vnb,
    u16* __restrict__ vt,
    float* __restrict__ oktq, float* __restrict__ ovtq,
    float* __restrict__ oksc, float* __restrict__ ovsc) {
    __shared__ u16 Vs[64][132];
    const int tid = threadIdx.x;
    const int bh = blockIdx.x >> 3, kt = blockIdx.x & 7;
    const int i0 = kt << 6;
    const int lane = tid & 63, w = tid >> 6;
    #pragma unroll 4
    for (int s = 0; s < 16; ++s) {
        const int key = s * 4 + w;
        const int i = i0 + key;
        u32 ku = *(const u32*)(kcb + ((size_t)bh * 4608 + 4096 + i) * 128 + lane * 2);
        u32 vu = *(const u32*)(vnb + ((size_t)bh * 512 + i) * 128 + lane * 2);
        float kx0 = bf2f((u16)ku), kx1 = bf2f((u16)(ku >> 16));
        float vx0 = bf2f((u16)vu), vx1 = bf2f((u16)(vu >> 16));
        *(u32*)&Vs[key][lane * 2] = vu;
        float kam = fmaxf(fabsf(kx0), fabsf(kx1));
        float vam = fmaxf(fabsf(vx0), fabsf(vx1));
        #pragma unroll
        for (int off = 1; off < 64; off <<= 1) {
            kam = fmaxf(kam, __shfl_xor(kam, off, 64));
            vam = fmaxf(vam, __shfl_xor(vam, off, 64));
        }
        float kscale = fmaxf(kam / 127.0f, 1e-8f);
        float vscale = fmaxf(vam / 127.0f, 1e-8f);
        float kinv = 1.0f / kscale, vinv = 1.0f / vscale;
        const size_t orow = (size_t)bh * 4096 + 3584 + i;
        f32x2 ko, vo;
        ko[0] = fminf(fmaxf(rintf(kx0 * kinv), -127.f), 127.f);
        ko[1] = fminf(fmaxf(rintf(kx1 * kinv), -127.f), 127.f);
        vo[0] = fminf(fmaxf(rintf(vx0 * vinv), -127.f), 127.f);
        vo[1] = fminf(fmaxf(rintf(vx1 * vinv), -127.f), 127.f);
        *(f32x2*)(oktq + orow * 128 + lane * 2) = ko;
        *(f32x2*)(ovtq + orow * 128 + lane * 2) = vo;
        if (lane == 0) {
            oksc[orow] = __half2float(__float2half(kscale));
            ovsc[orow] = __half2float(__float2half(vscale));
        }
    }
    __syncthreads();
    const int d = tid >> 1, half = tid & 1;
    u16* obase = vt + ((size_t)bh * 128 + d) * 4608 + 4096 + i0 + half * 32;
    #pragma unroll
    for (int c = 0; c < 4; ++c) {
        ushort8v tv;
        #pragma unroll
        for (int e = 0; e < 8; ++e) tv[e] = Vs[half * 32 + c * 8 + e][d];
        *(ushort8v*)(obase + c * 8) = tv;
    }
}

// ---------------------------------------------------------------------------
// attn: 256 blocks = (b,h) x 4 q-tiles of 128 rows, 8 waves. Uniform bf16 K
// buffer + V^T; gload_lds staging w/ XOR swizzle; 2-phase double buffer.
// ---------------------------------------------------------------------------
__global__ __launch_bounds__(512) void attn_kernel(
    const u16* __restrict__ qb, const u16* __restrict__ kcb,
    const u16* __restrict__ vt, u16* __restrict__ yb) {
    __shared__ u16 Ks[2][64 * 128];
    __shared__ u16 Vl[2][128 * 64];
    __shared__ u16 Pl[8][16][72];

    const int tid = threadIdx.x, lane = tid & 63, w = tid >> 6;
    const int p = blockIdx.x;
    const int bh = ((p >> 5) << 3) + (p & 7);   // p%8 == bh%8 -> same XCD per bh
    const int qt = (p >> 3) & 3;
    const int b = bh >> 4, h = bh & 15;
    const int r16 = lane & 15, kb = lane >> 4;

    const u16* qp = qb + ((size_t)bh * 512 + qt * 128 + w * 16 + r16) * 128;
    short8v qf[4];
    #pragma unroll
    for (int f = 0; f < 4; ++f)
        qf[f] = __builtin_bit_cast(short8v, *(const ushort8v*)(qp + f * 32 + kb * 8));

    f32x4 Of[8] = {};
    float m_i[4], l_i[4];
    #pragma unroll
    for (int v = 0; v < 4; ++v) { m_i[v] = -3.0e38f; l_i[v] = 0.f; }

    const size_t kbase = (size_t)bh * 4608 * 128;
    const size_t vbase = (size_t)bh * 128 * 4608;
    const int nt = 66 + qt * 2;

    auto STAGE = [&](int bi, int kt) {
        #pragma unroll
        for (int i = 0; i < 2; ++i) {
            int s = i * 512 + tid;
            int row = s >> 4, l = (s & 15) ^ (row & 7);
            gl_lds16(kcb + kbase + (size_t)(kt * 64 + row) * 128 + l * 8,
                     &Ks[bi][(i * 512 + (tid & ~63)) * 8]);
        }
        #pragma unroll
        for (int i = 0; i < 2; ++i) {
            int s = i * 512 + tid;
            int row = s >> 3, l = (s & 7) ^ (row & 7);
            gl_lds16(vt + vbase + (size_t)row * 4608 + kt * 64 + l * 8,
                     &Vl[bi][(i * 512 + (tid & ~63)) * 8]);
        }
    };

    STAGE(0, 0);
    __syncthreads();
    int cur = 0;
    for (int kt = 0; kt < nt; ++kt) {
        if (kt + 1 < nt) STAGE(cur ^ 1, kt + 1);

        // S = Q K^T : 16 x 64 per wave (scale pre-folded into W_q)
        f32x4 Sf[4] = {};
        __builtin_amdgcn_s_setprio(1);
        #pragma unroll
        for (int nf = 0; nf < 4; ++nf) {
            int krow = nf * 16 + r16;
            #pragma unroll
            for (int ksv = 0; ksv < 4; ++ksv) {
                int blk = (ksv * 4 + kb) ^ (krow & 7);
                short8v kf = __builtin_bit_cast(short8v,
                    *(const ushort8v*)&Ks[cur][krow * 128 + blk * 8]);
                Sf[nf] = __builtin_amdgcn_mfma_f32_16x16x32_bf16(qf[ksv], kf, Sf[nf], 0, 0, 0);
            }
        }
        __builtin_amdgcn_s_setprio(0);

        if (kt >= 64) {  // causal mask within the new segment
            const int jn0 = (kt - 64) * 64;
            const int qbase = qt * 128 + w * 16;
            #pragma unroll
            for (int nf = 0; nf < 4; ++nf) {
                int jn = jn0 + nf * 16 + r16;
                #pragma unroll
                for (int v = 0; v < 4; ++v)
                    if (jn > qbase + kb * 4 + v) Sf[nf][v] = -3.0e38f;
            }
        }

        // online softmax (row q=kb*4+v lives across the 16 r16 lanes)
        float alpha[4], rsum[4];
        #pragma unroll
        for (int v = 0; v < 4; ++v) {
            float mx = fmaxf(fmaxf(Sf[0][v], Sf[1][v]), fmaxf(Sf[2][v], Sf[3][v]));
            #pragma unroll
            for (int off = 1; off < 16; off <<= 1) mx = fmaxf(mx, __shfl_xor(mx, off, 64));
            float mnew = fmaxf(m_i[v], mx);
            alpha[v] = __expf(m_i[v] - mnew);
            m_i[v] = mnew;
            rsum[v] = 0.f;
        }
        #pragma unroll
        for (int nf = 0; nf < 4; ++nf)
            #pragma unroll
            for (int v = 0; v < 4; ++v) {
                float pq = __expf(Sf[nf][v] - m_i[v]);
                Sf[nf][v] = pq;
                rsum[v] += pq;
            }
        #pragma unroll
        for (int v = 0; v < 4; ++v) {
            float sm = rsum[v];
            #pragma unroll
            for (int off = 1; off < 16; off <<= 1) sm += __shfl_xor(sm, off, 64);
            l_i[v] = l_i[v] * alpha[v] + sm;
        }
        #pragma unroll
        for (int of = 0; of < 8; ++of)
            #pragma unroll
            for (int v = 0; v < 4; ++v) Of[of][v] *= alpha[v];

        // P -> LDS (bf16), wave-private
        #pragma unroll
        for (int nf = 0; nf < 4; ++nf)
            #pragma unroll
            for (int v = 0; v < 4; ++v)
                Pl[w][kb * 4 + v][nf * 16 + r16] = f2bf(Sf[nf][v]);
        asm volatile("s_waitcnt lgkmcnt(0)" ::: "memory");

        // O += P V
        __builtin_amdgcn_s_setprio(1);
        #pragma unroll
        for (int ka = 0; ka < 2; ++ka) {
            short8v pf = __builtin_bit_cast(short8v,
                *(const ushort8v*)&Pl[w][r16][ka * 32 + kb * 8]);
            #pragma unroll
            for (int of = 0; of < 8; ++of) {
                int vrow = of * 16 + r16;
                int blk = (ka * 4 + kb) ^ (vrow & 7);
                short8v vf = __builtin_bit_cast(short8v,
                    *(const ushort8v*)&Vl[cur][vrow * 64 + blk * 8]);
                Of[of] = __builtin_amdgcn_mfma_f32_16x16x32_bf16(pf, vf, Of[of], 0, 0, 0);
            }
        }
        __builtin_amdgcn_s_setprio(0);

        __syncthreads();
        cur ^= 1;
    }

    float invl[4];
    #pragma unroll
    for (int v = 0; v < 4; ++v) invl[v] = 1.0f / l_i[v];
    #pragma unroll
    for (int of = 0; of < 8; ++of)
        #pragma unroll
        for (int v = 0; v < 4; ++v) {
            int qrow = qt * 128 + w * 16 + kb * 4 + v;
            int d = of * 16 + r16;
            yb[(size_t)(b * 512 + qrow) * 2048 + h * 128 + d] = f2bf(Of[of][v] * invl[v]);
        }
}

// ---------------------------------------------------------------------------
extern "C" void kernel_launch(void* const* d_in, const int* in_sizes, int n_in,
                              void* d_out, int out_size, void* d_ws, size_t ws_size,
                              hipStream_t stream) {
    (void)in_sizes; (void)n_in; (void)out_size; (void)ws_size;
    const float* x   = (const float*)d_in[0];
    const int*   kq  = (const int*)d_in[1];
    const int*   vq  = (const int*)d_in[2];
    const float* ks  = (const float*)d_in[3];
    const float* vs  = (const float*)d_in[4];
    const float* Wq  = (const float*)d_in[5];
    const float* Wk  = (const float*)d_in[6];
    const float* Wv  = (const float*)d_in[7];
    const float* Wo  = (const float*)d_in[8];

    float* out  = (float*)d_out;
    float* y_o  = out;
    float* oktq = out + 4194304;
    float* ovtq = out + 37748736;
    float* oksc = out + 71303168;
    float* ovsc = out + 71565312;

    char* wsb = (char*)d_ws;
    u16* kcb = (u16*)(wsb);                       // 75.5 MB: [64][4608][128] bf16
    u16* vtb = (u16*)(wsb + 75497472);            // 75.5 MB: [64][128][4608] bf16
    u16* xb  = (u16*)(wsb + 150994944);           // 8 MB
    u16* wb  = (u16*)(wsb + 159383552);           // 8 MB (reused per GEMM)
    u16* qbf = (u16*)(wsb + 167772160);           // 8 MB
    u16* vnb = (u16*)(wsb + 176160768);           // 8 MB
    u16* ybf = (u16*)(wsb + 184549376);           // 8 MB

    const float rscale = 0.08838834764831845f;    // 1/sqrt(128)
    const int n8 = 2048 * 2048 / 8;

    prep_cache_kernel<<<4096, 256, 0, stream>>>(kq, vq, ks, vs, kcb, vtb,
                                                oktq, ovtq, oksc, ovsc);
    convert_kernel<<<2048, 256, 0, stream>>>(x, xb, 1.0f, n8);
    convert_kernel<<<2048, 256, 0, stream>>>(Wq, wb, rscale, n8);
    gemm_bf16_kernel<0><<<512, 256, 0, stream>>>(xb, wb, qbf);
    convert_kernel<<<2048, 256, 0, stream>>>(Wk, wb, 1.0f, n8);
    gemm_bf16_kernel<1><<<512, 256, 0, stream>>>(xb, wb, kcb);
    convert_kernel<<<2048, 256, 0, stream>>>(Wv, wb, 1.0f, n8);
    gemm_bf16_kernel<2><<<512, 256, 0, stream>>>(xb, wb, vnb);
    quant_new_kernel<<<512, 256, 0, stream>>>(kcb, vnb, vtb,
                                              oktq, ovtq, oksc, ovsc);
    attn_kernel<<<256, 512, 0, stream>>>(qbf, kcb, vtb, ybf);
    convert_kernel<<<2048, 256, 0, stream>>>(Wo, wb, 1.0f, n8);
    gemm_bf16_kernel<3><<<512, 256, 0, stream>>>(ybf, wb, y_o);
}

// Round 4
// 533.060 us; speedup vs baseline: 1.8017x; 1.0303x over previous
//
#include <hip/hip_runtime.h>
#include <hip/hip_fp16.h>

typedef float   f32x4   __attribute__((ext_vector_type(4)));
typedef float   f32x2   __attribute__((ext_vector_type(2)));
typedef short   short8v __attribute__((ext_vector_type(8)));
typedef unsigned short ushort8v __attribute__((ext_vector_type(8)));
typedef int     int2v   __attribute__((ext_vector_type(2)));
typedef unsigned int   u32;
typedef unsigned short u16;

#define DEVI static __device__ __forceinline__

DEVI u16 f2bf(float f) {
    u32 u = __builtin_bit_cast(u32, f);
    u += 0x7FFFu + ((u >> 16) & 1u);   // RNE (inputs finite)
    return (u16)(u >> 16);
}
DEVI float bf2f(u16 h) { return __builtin_bit_cast(float, (u32)h << 16); }

// async global->LDS, 16B per lane; lds ptr must be wave-uniform (lane*16 added by HW)
DEVI void gl_lds16(const u16* g, u16* l) {
    __builtin_amdgcn_global_load_lds(
        (const __attribute__((address_space(1))) u32*)(const void*)g,
        (__attribute__((address_space(3))) u32*)(void*)l, 16, 0, 0);
}

// ---------------------------------------------------------------------------
// convert f32 -> bf16 (optionally scaled). n8 = elements/8.
// ---------------------------------------------------------------------------
__global__ __launch_bounds__(256) void convert_kernel(
    const float* __restrict__ src, u16* __restrict__ dst, float scale, int n8) {
    int idx = blockIdx.x * 256 + threadIdx.x;
    if (idx >= n8) return;
    const float* p = src + (size_t)idx * 8;
    f32x4 a = *(const f32x4*)p, b = *(const f32x4*)(p + 4);
    ushort8v o;
    o[0]=f2bf(a[0]*scale); o[1]=f2bf(a[1]*scale); o[2]=f2bf(a[2]*scale); o[3]=f2bf(a[3]*scale);
    o[4]=f2bf(b[0]*scale); o[5]=f2bf(b[1]*scale); o[6]=f2bf(b[2]*scale); o[7]=f2bf(b[3]*scale);
    *(ushort8v*)(dst + (size_t)idx * 8) = o;
}

// ---------------------------------------------------------------------------
// prep_cache: dequant cache -> bf16 K rows (into kcb rows 0..4095) + bf16 V^T
// cols 0..4095 (transpose via LDS) + exact requant of window rows 512..4095.
// Grid 4096 = 64 bh * 64 tiles, 256 threads.
// ---------------------------------------------------------------------------
__global__ __launch_bounds__(256) void prep_cache_kernel(
    const int* __restrict__ kq, const int* __restrict__ vq,
    const float* __restrict__ ks, const float* __restrict__ vs,
    u16* __restrict__ kcb, u16* __restrict__ vt,
    float* __restrict__ oktq, float* __restrict__ ovtq,
    float* __restrict__ oksc, float* __restrict__ ovsc) {
    __shared__ u16 Vs[64][132];
    __shared__ float skL[64], svL[64];
    const int tid = threadIdx.x;
    const int bh = blockIdx.x >> 6, kt = blockIdx.x & 63;
    const int key0 = kt << 6;
    const size_t rowbase = (size_t)bh * 4096 + key0;
    if (tid < 64) { skL[tid] = ks[rowbase + tid]; svL[tid] = vs[rowbase + tid]; }
    __syncthreads();
    const int lane = tid & 63, w = tid >> 6;
    u32* kcw = (u32*)kcb;
    #pragma unroll 4
    for (int s = 0; s < 16; ++s) {
        const int key = s * 4 + w;
        const size_t row = rowbase + key;
        const float sk = skL[key], sv = svL[key];
        int2v kv = *(const int2v*)(kq + row * 128 + lane * 2);
        int2v vv = *(const int2v*)(vq + row * 128 + lane * 2);
        float kx0 = (float)kv[0] * sk, kx1 = (float)kv[1] * sk;
        float vx0 = (float)vv[0] * sv, vx1 = (float)vv[1] * sv;
        kcw[(size_t)(bh * 4608 + key0 + key) * 64 + lane] =
            (u32)f2bf(kx0) | ((u32)f2bf(kx1) << 16);
        *(u32*)&Vs[key][lane * 2] = (u32)f2bf(vx0) | ((u32)f2bf(vx1) << 16);
        float kam = fmaxf(fabsf(kx0), fabsf(kx1));
        float vam = fmaxf(fabsf(vx0), fabsf(vx1));
        #pragma unroll
        for (int off = 1; off < 64; off <<= 1) {
            kam = fmaxf(kam, __shfl_xor(kam, off, 64));
            vam = fmaxf(vam, __shfl_xor(vam, off, 64));
        }
        const int r = key0 + key;
        if (r >= 512) {
            const size_t orow = (size_t)bh * 4096 + (size_t)(r - 512);
            float kscale = fmaxf(kam / 127.0f, 1e-8f);
            float vscale = fmaxf(vam / 127.0f, 1e-8f);
            float kinv = 1.0f / kscale, vinv = 1.0f / vscale;
            f32x2 ko, vo;
            ko[0] = fminf(fmaxf(rintf(kx0 * kinv), -127.f), 127.f);
            ko[1] = fminf(fmaxf(rintf(kx1 * kinv), -127.f), 127.f);
            vo[0] = fminf(fmaxf(rintf(vx0 * vinv), -127.f), 127.f);
            vo[1] = fminf(fmaxf(rintf(vx1 * vinv), -127.f), 127.f);
            *(f32x2*)(oktq + orow * 128 + lane * 2) = ko;
            *(f32x2*)(ovtq + orow * 128 + lane * 2) = vo;
            if (lane == 0) {
                oksc[orow] = __half2float(__float2half(kscale));
                ovsc[orow] = __half2float(__float2half(vscale));
            }
        }
    }
    __syncthreads();
    const int d = tid >> 1, half = tid & 1;
    u16* obase = vt + ((size_t)bh * 128 + d) * 4608 + key0 + half * 32;
    #pragma unroll
    for (int c = 0; c < 4; ++c) {
        ushort8v tv;
        #pragma unroll
        for (int e = 0; e < 8; ++e) tv[e] = Vs[half * 32 + c * 8 + e][d];
        *(ushort8v*)(obase + c * 8) = tv;
    }
}

// ---------------------------------------------------------------------------
// bf16 GEMM  C[m][n] = sum_k A[m][k] * B[n][k]  (2048^3), BM=128 BN=64 BK=64,
// 256 thr (4 waves 2x2 of 64x32), gload_lds + XOR-swizzle + 2-phase dbuf.
// MODE 0: q bf16 head-split; 1: kcb bf16 rows 4096..; 2: vnb bf16 head-split;
// 3: f32 row-major.
// ---------------------------------------------------------------------------
template <int MODE>
__global__ __launch_bounds__(256) void gemm_bf16_kernel(
    const u16* __restrict__ A, const u16* __restrict__ Bw,
    void* __restrict__ Cout) {
    __shared__ u16 As[2][128 * 64];
    __shared__ u16 Bs[2][64 * 64];
    const int tid = threadIdx.x, lane = tid & 63, w = tid >> 6;
    const int sid = (blockIdx.x & 7) * 64 + (blockIdx.x >> 3);  // XCD-chunked
    const int bm = sid & 15, bn = sid >> 4;
    const int m0 = bm * 128, n0 = bn * 64;
    const int wm = (w >> 1) * 64, wn = (w & 1) * 32;
    const int r16 = lane & 15, kb = lane >> 4;

    f32x4 acc[4][2] = {};

    auto stage = [&](int bi, int k0) {
        #pragma unroll
        for (int i = 0; i < 4; ++i) {
            int s = i * 256 + tid;
            int row = s >> 3, l = (s & 7) ^ (row & 7);
            gl_lds16(A + (size_t)(m0 + row) * 2048 + k0 + l * 8,
                     &As[bi][(i * 256 + (tid & ~63)) * 8]);
        }
        #pragma unroll
        for (int i = 0; i < 2; ++i) {
            int s = i * 256 + tid;
            int row = s >> 3, l = (s & 7) ^ (row & 7);
            gl_lds16(Bw + (size_t)(n0 + row) * 2048 + k0 + l * 8,
                     &Bs[bi][(i * 256 + (tid & ~63)) * 8]);
        }
    };

    stage(0, 0);
    __syncthreads();
    int cur = 0;
    for (int t = 0; t < 32; ++t) {
        if (t < 31) stage(cur ^ 1, (t + 1) * 64);
        short8v af[4][2], bf[2][2];
        #pragma unroll
        for (int mf = 0; mf < 4; ++mf) {
            int row = wm + mf * 16 + r16;
            #pragma unroll
            for (int ksv = 0; ksv < 2; ++ksv) {
                int blk = (ksv * 4 + kb) ^ (row & 7);
                af[mf][ksv] = __builtin_bit_cast(short8v,
                    *(const ushort8v*)&As[cur][row * 64 + blk * 8]);
            }
        }
        #pragma unroll
        for (int nf = 0; nf < 2; ++nf) {
            int row = wn + nf * 16 + r16;
            #pragma unroll
            for (int ksv = 0; ksv < 2; ++ksv) {
                int blk = (ksv * 4 + kb) ^ (row & 7);
                bf[nf][ksv] = __builtin_bit_cast(short8v,
                    *(const ushort8v*)&Bs[cur][row * 64 + blk * 8]);
            }
        }
        #pragma unroll
        for (int mf = 0; mf < 4; ++mf)
            #pragma unroll
            for (int nf = 0; nf < 2; ++nf)
                #pragma unroll
                for (int ksv = 0; ksv < 2; ++ksv)
                    acc[mf][nf] = __builtin_amdgcn_mfma_f32_16x16x32_bf16(
                        af[mf][ksv], bf[nf][ksv], acc[mf][nf], 0, 0, 0);
        __syncthreads();
        cur ^= 1;
    }

    #pragma unroll
    for (int mf = 0; mf < 4; ++mf)
        #pragma unroll
        for (int nf = 0; nf < 2; ++nf)
            #pragma unroll
            for (int v = 0; v < 4; ++v) {
                int mg = m0 + wm + mf * 16 + kb * 4 + v;
                int ng = n0 + wn + nf * 16 + r16;
                float val = acc[mf][nf][v];
                if (MODE == 0 || MODE == 2) {
                    ((u16*)Cout)[(((size_t)(mg >> 9) * 16 + (ng >> 7)) * 512 +
                                  (mg & 511)) * 128 + (ng & 127)] = f2bf(val);
                } else if (MODE == 1) {
                    size_t bh = (size_t)(mg >> 9) * 16 + (ng >> 7);
                    ((u16*)Cout)[(bh * 4608 + 4096 + (mg & 511)) * 128 + (ng & 127)] = f2bf(val);
                } else {
                    ((float*)Cout)[(size_t)mg * 2048 + ng] = val;
                }
            }
}

// ---------------------------------------------------------------------------
// quant_new: quantize new K/V rows (from bf16 kcb rows 4096.., vnb) + V^T
// cols 4096..4607. Grid 512 = 64 bh * 8 tiles, 256 threads.
// ---------------------------------------------------------------------------
__global__ __launch_bounds__(256) void quant_new_kernel(
    const u16* __restrict__ kcb, const u16* __restrict__ vnb,
    u16* __restrict__ vt,
    float* __restrict__ oktq, float* __restrict__ ovtq,
    float* __restrict__ oksc, float* __restrict__ ovsc) {
    __shared__ u16 Vs[64][132];
    const int tid = threadIdx.x;
    const int bh = blockIdx.x >> 3, kt = blockIdx.x & 7;
    const int i0 = kt << 6;
    const int lane = tid & 63, w = tid >> 6;
    #pragma unroll 4
    for (int s = 0; s < 16; ++s) {
        const int key = s * 4 + w;
        const int i = i0 + key;
        u32 ku = *(const u32*)(kcb + ((size_t)bh * 4608 + 4096 + i) * 128 + lane * 2);
        u32 vu = *(const u32*)(vnb + ((size_t)bh * 512 + i) * 128 + lane * 2);
        float kx0 = bf2f((u16)ku), kx1 = bf2f((u16)(ku >> 16));
        float vx0 = bf2f((u16)vu), vx1 = bf2f((u16)(vu >> 16));
        *(u32*)&Vs[key][lane * 2] = vu;
        float kam = fmaxf(fabsf(kx0), fabsf(kx1));
        float vam = fmaxf(fabsf(vx0), fabsf(vx1));
        #pragma unroll
        for (int off = 1; off < 64; off <<= 1) {
            kam = fmaxf(kam, __shfl_xor(kam, off, 64));
            vam = fmaxf(vam, __shfl_xor(vam, off, 64));
        }
        float kscale = fmaxf(kam / 127.0f, 1e-8f);
        float vscale = fmaxf(vam / 127.0f, 1e-8f);
        float kinv = 1.0f / kscale, vinv = 1.0f / vscale;
        const size_t orow = (size_t)bh * 4096 + 3584 + i;
        f32x2 ko, vo;
        ko[0] = fminf(fmaxf(rintf(kx0 * kinv), -127.f), 127.f);
        ko[1] = fminf(fmaxf(rintf(kx1 * kinv), -127.f), 127.f);
        vo[0] = fminf(fmaxf(rintf(vx0 * vinv), -127.f), 127.f);
        vo[1] = fminf(fmaxf(rintf(vx1 * vinv), -127.f), 127.f);
        *(f32x2*)(oktq + orow * 128 + lane * 2) = ko;
        *(f32x2*)(ovtq + orow * 128 + lane * 2) = vo;
        if (lane == 0) {
            oksc[orow] = __half2float(__float2half(kscale));
            ovsc[orow] = __half2float(__float2half(vscale));
        }
    }
    __syncthreads();
    const int d = tid >> 1, half = tid & 1;
    u16* obase = vt + ((size_t)bh * 128 + d) * 4608 + 4096 + i0 + half * 32;
    #pragma unroll
    for (int c = 0; c < 4; ++c) {
        ushort8v tv;
        #pragma unroll
        for (int e = 0; e < 8; ++e) tv[e] = Vs[half * 32 + c * 8 + e][d];
        *(ushort8v*)(obase + c * 8) = tv;
    }
}

// ---------------------------------------------------------------------------
// attn: 512 blocks = (b,h) x 8 q-tiles of 64 rows, 4 waves (16 q-rows each).
// 2 blocks/CU (LDS 73KB) -> two independent barrier domains per CU.
// Defer-max (THR=8) + per-lane partial l (single epilogue reduce).
// ---------------------------------------------------------------------------
__global__ __launch_bounds__(256) void attn_kernel(
    const u16* __restrict__ qb, const u16* __restrict__ kcb,
    const u16* __restrict__ vt, u16* __restrict__ yb) {
    __shared__ u16 Ks[2][64 * 128];
    __shared__ u16 Vl[2][128 * 64];
    __shared__ u16 Pl[4][16][72];

    const int tid = threadIdx.x, lane = tid & 63, w = tid >> 6;
    const int p = blockIdx.x;
    const int bh = ((p >> 6) << 3) | (p & 7);   // p%8 == bh%8 -> same XCD per bh
    const int qt = (p >> 3) & 7;
    const int b = bh >> 4, h = bh & 15;
    const int r16 = lane & 15, kb = lane >> 4;

    const u16* qp = qb + ((size_t)bh * 512 + qt * 64 + w * 16 + r16) * 128;
    short8v qf[4];
    #pragma unroll
    for (int f = 0; f < 4; ++f)
        qf[f] = __builtin_bit_cast(short8v, *(const ushort8v*)(qp + f * 32 + kb * 8));

    f32x4 Of[8] = {};
    float m_i[4], l_i[4];
    #pragma unroll
    for (int v = 0; v < 4; ++v) { m_i[v] = -3.0e38f; l_i[v] = 0.f; }

    const size_t kbase = (size_t)bh * 4608 * 128;
    const size_t vbase = (size_t)bh * 128 * 4608;
    const int nt = 65 + qt;

    auto STAGE = [&](int bi, int kt) {
        #pragma unroll
        for (int i = 0; i < 4; ++i) {
            int s = i * 256 + tid;
            int row = s >> 4, l = (s & 15) ^ (row & 7);
            gl_lds16(kcb + kbase + (size_t)(kt * 64 + row) * 128 + l * 8,
                     &Ks[bi][(i * 256 + (tid & ~63)) * 8]);
        }
        #pragma unroll
        for (int i = 0; i < 4; ++i) {
            int s = i * 256 + tid;
            int row = s >> 3, l = (s & 7) ^ (row & 7);
            gl_lds16(vt + vbase + (size_t)row * 4608 + kt * 64 + l * 8,
                     &Vl[bi][(i * 256 + (tid & ~63)) * 8]);
        }
    };

    STAGE(0, 0);
    __syncthreads();
    int cur = 0;
    for (int kt = 0; kt < nt; ++kt) {
        if (kt + 1 < nt) STAGE(cur ^ 1, kt + 1);

        // S = Q K^T : 16 x 64 per wave (scale pre-folded into W_q)
        f32x4 Sf[4] = {};
        __builtin_amdgcn_s_setprio(1);
        #pragma unroll
        for (int nf = 0; nf < 4; ++nf) {
            int krow = nf * 16 + r16;
            #pragma unroll
            for (int ksv = 0; ksv < 4; ++ksv) {
                int blk = (ksv * 4 + kb) ^ (krow & 7);
                short8v kf = __builtin_bit_cast(short8v,
                    *(const ushort8v*)&Ks[cur][krow * 128 + blk * 8]);
                Sf[nf] = __builtin_amdgcn_mfma_f32_16x16x32_bf16(qf[ksv], kf, Sf[nf], 0, 0, 0);
            }
        }
        __builtin_amdgcn_s_setprio(0);

        if (kt >= 64) {  // causal mask within the new segment
            const int jn0 = (kt - 64) * 64;
            const int qbase = qt * 64 + w * 16;
            #pragma unroll
            for (int nf = 0; nf < 4; ++nf) {
                int jn = jn0 + nf * 16 + r16;
                #pragma unroll
                for (int v = 0; v < 4; ++v)
                    if (jn > qbase + kb * 4 + v) Sf[nf][v] = -3.0e38f;
            }
        }

        // row max (q = kb*4+v, across the 16 r16 lanes)
        float mx[4];
        #pragma unroll
        for (int v = 0; v < 4; ++v) {
            float t = fmaxf(fmaxf(Sf[0][v], Sf[1][v]), fmaxf(Sf[2][v], Sf[3][v]));
            #pragma unroll
            for (int off = 1; off < 16; off <<= 1) t = fmaxf(t, __shfl_xor(t, off, 64));
            mx[v] = t;
        }
        // defer-max: rescale only when some row grew past m+8
        bool need = (mx[0] > m_i[0] + 8.f) || (mx[1] > m_i[1] + 8.f) ||
                    (mx[2] > m_i[2] + 8.f) || (mx[3] > m_i[3] + 8.f);
        if (__ballot(need)) {
            #pragma unroll
            for (int v = 0; v < 4; ++v) {
                float mnew = fmaxf(m_i[v], mx[v]);
                float alpha = __expf(m_i[v] - mnew);
                m_i[v] = mnew;
                l_i[v] *= alpha;
                #pragma unroll
                for (int of = 0; of < 8; ++of) Of[of][v] *= alpha;
            }
        }
        // P = exp(S - m), accumulate per-lane partial l
        #pragma unroll
        for (int v = 0; v < 4; ++v) {
            float s0 = __expf(Sf[0][v] - m_i[v]);
            float s1 = __expf(Sf[1][v] - m_i[v]);
            float s2 = __expf(Sf[2][v] - m_i[v]);
            float s3 = __expf(Sf[3][v] - m_i[v]);
            Sf[0][v] = s0; Sf[1][v] = s1; Sf[2][v] = s2; Sf[3][v] = s3;
            l_i[v] += (s0 + s1) + (s2 + s3);
        }

        // P -> LDS (bf16), wave-private
        #pragma unroll
        for (int nf = 0; nf < 4; ++nf)
            #pragma unroll
            for (int v = 0; v < 4; ++v)
                Pl[w][kb * 4 + v][nf * 16 + r16] = f2bf(Sf[nf][v]);
        asm volatile("s_waitcnt lgkmcnt(0)" ::: "memory");

        // O += P V
        __builtin_amdgcn_s_setprio(1);
        #pragma unroll
        for (int ka = 0; ka < 2; ++ka) {
            short8v pf = __builtin_bit_cast(short8v,
                *(const ushort8v*)&Pl[w][r16][ka * 32 + kb * 8]);
            #pragma unroll
            for (int of = 0; of < 8; ++of) {
                int vrow = of * 16 + r16;
                int blk = (ka * 4 + kb) ^ (vrow & 7);
                short8v vf = __builtin_bit_cast(short8v,
                    *(const ushort8v*)&Vl[cur][vrow * 64 + blk * 8]);
                Of[of] = __builtin_amdgcn_mfma_f32_16x16x32_bf16(pf, vf, Of[of], 0, 0, 0);
            }
        }
        __builtin_amdgcn_s_setprio(0);

        __syncthreads();
        cur ^= 1;
    }

    float invl[4];
    #pragma unroll
    for (int v = 0; v < 4; ++v) {
        float sm = l_i[v];
        #pragma unroll
        for (int off = 1; off < 16; off <<= 1) sm += __shfl_xor(sm, off, 64);
        invl[v] = 1.0f / sm;
    }
    #pragma unroll
    for (int of = 0; of < 8; ++of)
        #pragma unroll
        for (int v = 0; v < 4; ++v) {
            int qrow = qt * 64 + w * 16 + kb * 4 + v;
            int d = of * 16 + r16;
            yb[(size_t)(b * 512 + qrow) * 2048 + h * 128 + d] = f2bf(Of[of][v] * invl[v]);
        }
}

// ---------------------------------------------------------------------------
extern "C" void kernel_launch(void* const* d_in, const int* in_sizes, int n_in,
                              void* d_out, int out_size, void* d_ws, size_t ws_size,
                              hipStream_t stream) {
    (void)in_sizes; (void)n_in; (void)out_size; (void)ws_size;
    const float* x   = (const float*)d_in[0];
    const int*   kq  = (const int*)d_in[1];
    const int*   vq  = (const int*)d_in[2];
    const float* ks  = (const float*)d_in[3];
    const float* vs  = (const float*)d_in[4];
    const float* Wq  = (const float*)d_in[5];
    const float* Wk  = (const float*)d_in[6];
    const float* Wv  = (const float*)d_in[7];
    const float* Wo  = (const float*)d_in[8];

    float* out  = (float*)d_out;
    float* y_o  = out;
    float* oktq = out + 4194304;
    float* ovtq = out + 37748736;
    float* oksc = out + 71303168;
    float* ovsc = out + 71565312;

    char* wsb = (char*)d_ws;
    u16* kcb = (u16*)(wsb);                       // 75.5 MB: [64][4608][128] bf16
    u16* vtb = (u16*)(wsb + 75497472);            // 75.5 MB: [64][128][4608] bf16
    u16* xb  = (u16*)(wsb + 150994944);           // 8 MB
    u16* wb  = (u16*)(wsb + 159383552);           // 8 MB (reused per GEMM)
    u16* qbf = (u16*)(wsb + 167772160);           // 8 MB
    u16* vnb = (u16*)(wsb + 176160768);           // 8 MB
    u16* ybf = (u16*)(wsb + 184549376);           // 8 MB

    const float rscale = 0.08838834764831845f;    // 1/sqrt(128)
    const int n8 = 2048 * 2048 / 8;

    prep_cache_kernel<<<4096, 256, 0, stream>>>(kq, vq, ks, vs, kcb, vtb,
                                                oktq, ovtq, oksc, ovsc);
    convert_kernel<<<2048, 256, 0, stream>>>(x, xb, 1.0f, n8);
    convert_kernel<<<2048, 256, 0, stream>>>(Wq, wb, rscale, n8);
    gemm_bf16_kernel<0><<<512, 256, 0, stream>>>(xb, wb, qbf);
    convert_kernel<<<2048, 256, 0, stream>>>(Wk, wb, 1.0f, n8);
    gemm_bf16_kernel<1><<<512, 256, 0, stream>>>(xb, wb, kcb);
    convert_kernel<<<2048, 256, 0, stream>>>(Wv, wb, 1.0f, n8);
    gemm_bf16_kernel<2><<<512, 256, 0, stream>>>(xb, wb, vnb);
    quant_new_kernel<<<512, 256, 0, stream>>>(kcb, vnb, vtb,
                                              oktq, ovtq, oksc, ovsc);
    attn_kernel<<<512, 256, 0, stream>>>(qbf, kcb, vtb, ybf);
    convert_kernel<<<2048, 256, 0, stream>>>(Wo, wb, 1.0f, n8);
    gemm_bf16_kernel<3><<<512, 256, 0, stream>>>(ybf, wb, y_o);
}

// Round 5
// 503.218 us; speedup vs baseline: 1.9086x; 1.0593x over previous
//
#include <hip/hip_runtime.h>
#include <hip/hip_fp16.h>

typedef float   f32x4   __attribute__((ext_vector_type(4)));
typedef float   f32x2   __attribute__((ext_vector_type(2)));
typedef short   short8v __attribute__((ext_vector_type(8)));
typedef unsigned short ushort8v __attribute__((ext_vector_type(8)));
typedef int     int2v   __attribute__((ext_vector_type(2)));
typedef unsigned int   u32;
typedef unsigned short u16;

#define DEVI static __device__ __forceinline__

DEVI u16 f2bf(float f) {
    u32 u = __builtin_bit_cast(u32, f);
    u += 0x7FFFu + ((u >> 16) & 1u);   // RNE (inputs finite)
    return (u16)(u >> 16);
}
DEVI float bf2f(u16 h) { return __builtin_bit_cast(float, (u32)h << 16); }

// async global->LDS, 16B per lane; lds ptr must be wave-uniform (lane*16 added by HW)
DEVI void gl_lds16(const u16* g, u16* l) {
    __builtin_amdgcn_global_load_lds(
        (const __attribute__((address_space(1))) u32*)(const void*)g,
        (__attribute__((address_space(3))) u32*)(void*)l, 16, 0, 0);
}

// ---------------------------------------------------------------------------
// convert f32 -> bf16 (optionally scaled). n8 = elements/8.
// ---------------------------------------------------------------------------
__global__ __launch_bounds__(256) void convert_kernel(
    const float* __restrict__ src, u16* __restrict__ dst, float scale, int n8) {
    int idx = blockIdx.x * 256 + threadIdx.x;
    if (idx >= n8) return;
    const float* p = src + (size_t)idx * 8;
    f32x4 a = *(const f32x4*)p, b = *(const f32x4*)(p + 4);
    ushort8v o;
    o[0]=f2bf(a[0]*scale); o[1]=f2bf(a[1]*scale); o[2]=f2bf(a[2]*scale); o[3]=f2bf(a[3]*scale);
    o[4]=f2bf(b[0]*scale); o[5]=f2bf(b[1]*scale); o[6]=f2bf(b[2]*scale); o[7]=f2bf(b[3]*scale);
    *(ushort8v*)(dst + (size_t)idx * 8) = o;
}

// ---------------------------------------------------------------------------
// prep_cache: dequant cache -> bf16 K rows (into kcb rows 0..4095) + bf16 V^T
// cols 0..4095 (transpose via LDS) + exact requant of window rows 512..4095.
// Grid 4096 = 64 bh * 64 tiles, 256 threads.
// ---------------------------------------------------------------------------
__global__ __launch_bounds__(256) void prep_cache_kernel(
    const int* __restrict__ kq, const int* __restrict__ vq,
    const float* __restrict__ ks, const float* __restrict__ vs,
    u16* __restrict__ kcb, u16* __restrict__ vt,
    float* __restrict__ oktq, float* __restrict__ ovtq,
    float* __restrict__ oksc, float* __restrict__ ovsc) {
    __shared__ u16 Vs[64][132];
    __shared__ float skL[64], svL[64];
    const int tid = threadIdx.x;
    const int bh = blockIdx.x >> 6, kt = blockIdx.x & 63;
    const int key0 = kt << 6;
    const size_t rowbase = (size_t)bh * 4096 + key0;
    if (tid < 64) { skL[tid] = ks[rowbase + tid]; svL[tid] = vs[rowbase + tid]; }
    __syncthreads();
    const int lane = tid & 63, w = tid >> 6;
    u32* kcw = (u32*)kcb;
    #pragma unroll 4
    for (int s = 0; s < 16; ++s) {
        const int key = s * 4 + w;
        const size_t row = rowbase + key;
        const float sk = skL[key], sv = svL[key];
        int2v kv = *(const int2v*)(kq + row * 128 + lane * 2);
        int2v vv = *(const int2v*)(vq + row * 128 + lane * 2);
        float kx0 = (float)kv[0] * sk, kx1 = (float)kv[1] * sk;
        float vx0 = (float)vv[0] * sv, vx1 = (float)vv[1] * sv;
        kcw[(size_t)(bh * 4608 + key0 + key) * 64 + lane] =
            (u32)f2bf(kx0) | ((u32)f2bf(kx1) << 16);
        *(u32*)&Vs[key][lane * 2] = (u32)f2bf(vx0) | ((u32)f2bf(vx1) << 16);
        float kam = fmaxf(fabsf(kx0), fabsf(kx1));
        float vam = fmaxf(fabsf(vx0), fabsf(vx1));
        #pragma unroll
        for (int off = 1; off < 64; off <<= 1) {
            kam = fmaxf(kam, __shfl_xor(kam, off, 64));
            vam = fmaxf(vam, __shfl_xor(vam, off, 64));
        }
        const int r = key0 + key;
        if (r >= 512) {
            const size_t orow = (size_t)bh * 4096 + (size_t)(r - 512);
            float kscale = fmaxf(kam / 127.0f, 1e-8f);
            float vscale = fmaxf(vam / 127.0f, 1e-8f);
            float kinv = 1.0f / kscale, vinv = 1.0f / vscale;
            f32x2 ko, vo;
            ko[0] = fminf(fmaxf(rintf(kx0 * kinv), -127.f), 127.f);
            ko[1] = fminf(fmaxf(rintf(kx1 * kinv), -127.f), 127.f);
            vo[0] = fminf(fmaxf(rintf(vx0 * vinv), -127.f), 127.f);
            vo[1] = fminf(fmaxf(rintf(vx1 * vinv), -127.f), 127.f);
            *(f32x2*)(oktq + orow * 128 + lane * 2) = ko;
            *(f32x2*)(ovtq + orow * 128 + lane * 2) = vo;
            if (lane == 0) {
                oksc[orow] = __half2float(__float2half(kscale));
                ovsc[orow] = __half2float(__float2half(vscale));
            }
        }
    }
    __syncthreads();
    const int d = tid >> 1, half = tid & 1;
    u16* obase = vt + ((size_t)bh * 128 + d) * 4608 + key0 + half * 32;
    #pragma unroll
    for (int c = 0; c < 4; ++c) {
        ushort8v tv;
        #pragma unroll
        for (int e = 0; e < 8; ++e) tv[e] = Vs[half * 32 + c * 8 + e][d];
        *(ushort8v*)(obase + c * 8) = tv;
    }
}

// ---------------------------------------------------------------------------
// bf16 GEMM  C[m][n] = sum_k A[m][k] * B[n][k]  (2048^3), BM=128 BN=64 BK=64,
// 256 thr (4 waves 2x2 of 64x32), gload_lds + XOR-swizzle + 2-phase dbuf.
// MODE 0: q bf16 head-split; 1: kcb bf16 rows 4096..; 2: vnb bf16 head-split;
// 3: f32 row-major.
// ---------------------------------------------------------------------------
template <int MODE>
__global__ __launch_bounds__(256) void gemm_bf16_kernel(
    const u16* __restrict__ A, const u16* __restrict__ Bw,
    void* __restrict__ Cout) {
    __shared__ u16 As[2][128 * 64];
    __shared__ u16 Bs[2][64 * 64];
    const int tid = threadIdx.x, lane = tid & 63, w = tid >> 6;
    const int sid = (blockIdx.x & 7) * 64 + (blockIdx.x >> 3);  // XCD-chunked
    const int bm = sid & 15, bn = sid >> 4;
    const int m0 = bm * 128, n0 = bn * 64;
    const int wm = (w >> 1) * 64, wn = (w & 1) * 32;
    const int r16 = lane & 15, kb = lane >> 4;

    f32x4 acc[4][2] = {};

    auto stage = [&](int bi, int k0) {
        #pragma unroll
        for (int i = 0; i < 4; ++i) {
            int s = i * 256 + tid;
            int row = s >> 3, l = (s & 7) ^ (row & 7);
            gl_lds16(A + (size_t)(m0 + row) * 2048 + k0 + l * 8,
                     &As[bi][(i * 256 + (tid & ~63)) * 8]);
        }
        #pragma unroll
        for (int i = 0; i < 2; ++i) {
            int s = i * 256 + tid;
            int row = s >> 3, l = (s & 7) ^ (row & 7);
            gl_lds16(Bw + (size_t)(n0 + row) * 2048 + k0 + l * 8,
                     &Bs[bi][(i * 256 + (tid & ~63)) * 8]);
        }
    };

    stage(0, 0);
    __syncthreads();
    int cur = 0;
    for (int t = 0; t < 32; ++t) {
        if (t < 31) stage(cur ^ 1, (t + 1) * 64);
        short8v af[4][2], bf[2][2];
        #pragma unroll
        for (int mf = 0; mf < 4; ++mf) {
            int row = wm + mf * 16 + r16;
            #pragma unroll
            for (int ksv = 0; ksv < 2; ++ksv) {
                int blk = (ksv * 4 + kb) ^ (row & 7);
                af[mf][ksv] = __builtin_bit_cast(short8v,
                    *(const ushort8v*)&As[cur][row * 64 + blk * 8]);
            }
        }
        #pragma unroll
        for (int nf = 0; nf < 2; ++nf) {
            int row = wn + nf * 16 + r16;
            #pragma unroll
            for (int ksv = 0; ksv < 2; ++ksv) {
                int blk = (ksv * 4 + kb) ^ (row & 7);
                bf[nf][ksv] = __builtin_bit_cast(short8v,
                    *(const ushort8v*)&Bs[cur][row * 64 + blk * 8]);
            }
        }
        #pragma unroll
        for (int mf = 0; mf < 4; ++mf)
            #pragma unroll
            for (int nf = 0; nf < 2; ++nf)
                #pragma unroll
                for (int ksv = 0; ksv < 2; ++ksv)
                    acc[mf][nf] = __builtin_amdgcn_mfma_f32_16x16x32_bf16(
                        af[mf][ksv], bf[nf][ksv], acc[mf][nf], 0, 0, 0);
        __syncthreads();
        cur ^= 1;
    }

    #pragma unroll
    for (int mf = 0; mf < 4; ++mf)
        #pragma unroll
        for (int nf = 0; nf < 2; ++nf)
            #pragma unroll
            for (int v = 0; v < 4; ++v) {
                int mg = m0 + wm + mf * 16 + kb * 4 + v;
                int ng = n0 + wn + nf * 16 + r16;
                float val = acc[mf][nf][v];
                if (MODE == 0 || MODE == 2) {
                    ((u16*)Cout)[(((size_t)(mg >> 9) * 16 + (ng >> 7)) * 512 +
                                  (mg & 511)) * 128 + (ng & 127)] = f2bf(val);
                } else if (MODE == 1) {
                    size_t bh = (size_t)(mg >> 9) * 16 + (ng >> 7);
                    ((u16*)Cout)[(bh * 4608 + 4096 + (mg & 511)) * 128 + (ng & 127)] = f2bf(val);
                } else {
                    ((float*)Cout)[(size_t)mg * 2048 + ng] = val;
                }
            }
}

// ---------------------------------------------------------------------------
// quant_new: quantize new K/V rows (from bf16 kcb rows 4096.., vnb) + V^T
// cols 4096..4607. Grid 512 = 64 bh * 8 tiles, 256 threads.
// ---------------------------------------------------------------------------
__global__ __launch_bounds__(256) void quant_new_kernel(
    const u16* __restrict__ kcb, const u16* __restrict__ vnb,
    u16* __restrict__ vt,
    float* __restrict__ oktq, float* __restrict__ ovtq,
    float* __restrict__ oksc, float* __restrict__ ovsc) {
    __shared__ u16 Vs[64][132];
    const int tid = threadIdx.x;
    const int bh = blockIdx.x >> 3, kt = blockIdx.x & 7;
    const int i0 = kt << 6;
    const int lane = tid & 63, w = tid >> 6;
    #pragma unroll 4
    for (int s = 0; s < 16; ++s) {
        const int key = s * 4 + w;
        const int i = i0 + key;
        u32 ku = *(const u32*)(kcb + ((size_t)bh * 4608 + 4096 + i) * 128 + lane * 2);
        u32 vu = *(const u32*)(vnb + ((size_t)bh * 512 + i) * 128 + lane * 2);
        float kx0 = bf2f((u16)ku), kx1 = bf2f((u16)(ku >> 16));
        float vx0 = bf2f((u16)vu), vx1 = bf2f((u16)(vu >> 16));
        *(u32*)&Vs[key][lane * 2] = vu;
        float kam = fmaxf(fabsf(kx0), fabsf(kx1));
        float vam = fmaxf(fabsf(vx0), fabsf(vx1));
        #pragma unroll
        for (int off = 1; off < 64; off <<= 1) {
            kam = fmaxf(kam, __shfl_xor(kam, off, 64));
            vam = fmaxf(vam, __shfl_xor(vam, off, 64));
        }
        float kscale = fmaxf(kam / 127.0f, 1e-8f);
        float vscale = fmaxf(vam / 127.0f, 1e-8f);
        float kinv = 1.0f / kscale, vinv = 1.0f / vscale;
        const size_t orow = (size_t)bh * 4096 + 3584 + i;
        f32x2 ko, vo;
        ko[0] = fminf(fmaxf(rintf(kx0 * kinv), -127.f), 127.f);
        ko[1] = fminf(fmaxf(rintf(kx1 * kinv), -127.f), 127.f);
        vo[0] = fminf(fmaxf(rintf(vx0 * vinv), -127.f), 127.f);
        vo[1] = fminf(fmaxf(rintf(vx1 * vinv), -127.f), 127.f);
        *(f32x2*)(oktq + orow * 128 + lane * 2) = ko;
        *(f32x2*)(ovtq + orow * 128 + lane * 2) = vo;
        if (lane == 0) {
            oksc[orow] = __half2float(__float2half(kscale));
            ovsc[orow] = __half2float(__float2half(vscale));
        }
    }
    __syncthreads();
    const int d = tid >> 1, half = tid & 1;
    u16* obase = vt + ((size_t)bh * 128 + d) * 4608 + 4096 + i0 + half * 32;
    #pragma unroll
    for (int c = 0; c < 4; ++c) {
        ushort8v tv;
        #pragma unroll
        for (int e = 0; e < 8; ++e) tv[e] = Vs[half * 32 + c * 8 + e][d];
        *(ushort8v*)(obase + c * 8) = tv;
    }
}

// ---------------------------------------------------------------------------
// attn: 512 blocks = (b,h) x 8 q-tiles of 64 rows, 4 waves (16 q-rows each).
// SWAPPED QK^T (mfma(K,Q)) -> S lane-local per q-row r16: softmax is a local
// 16-reg tree + 2 shuffles. P repacked via v_cvt_pk_bf16_f32 into padded u32
// LDS rows (4x ds_write_b64 + 2x ds_read_b128). Defer-max THR=8.
// ---------------------------------------------------------------------------
__global__ __launch_bounds__(256) void attn_kernel(
    const u16* __restrict__ qb, const u16* __restrict__ kcb,
    const u16* __restrict__ vt, u16* __restrict__ yb) {
    __shared__ u16 Ks[2][64 * 128];
    __shared__ u16 Vl[2][128 * 64];
    __shared__ u32 Pl[4][16][36];   // [wave][q-row r16][k-word], +4 pad words

    const int tid = threadIdx.x, lane = tid & 63, w = tid >> 6;
    const int p = blockIdx.x;
    const int bh = ((p >> 6) << 3) | (p & 7);   // p%8 == bh%8 -> same XCD per bh
    const int qt = (p >> 3) & 7;
    const int b = bh >> 4, h = bh & 15;
    const int r16 = lane & 15, kb = lane >> 4;

    const u16* qp = qb + ((size_t)bh * 512 + qt * 64 + w * 16 + r16) * 128;
    short8v qf[4];
    #pragma unroll
    for (int f = 0; f < 4; ++f)
        qf[f] = __builtin_bit_cast(short8v, *(const ushort8v*)(qp + f * 32 + kb * 8));

    f32x4 Of[8] = {};
    float m_i = -3.0e38f, l_i = 0.f;   // per-lane: q-row = r16 (+ base)

    const size_t kbase = (size_t)bh * 4608 * 128;
    const size_t vbase = (size_t)bh * 128 * 4608;
    const int nt = 65 + qt;

    auto STAGE = [&](int bi, int kt) {
        #pragma unroll
        for (int i = 0; i < 4; ++i) {
            int s = i * 256 + tid;
            int row = s >> 4, l = (s & 15) ^ (row & 7);
            gl_lds16(kcb + kbase + (size_t)(kt * 64 + row) * 128 + l * 8,
                     &Ks[bi][(i * 256 + (tid & ~63)) * 8]);
        }
        #pragma unroll
        for (int i = 0; i < 4; ++i) {
            int s = i * 256 + tid;
            int row = s >> 3, l = (s & 7) ^ (row & 7);
            gl_lds16(vt + vbase + (size_t)row * 4608 + kt * 64 + l * 8,
                     &Vl[bi][(i * 256 + (tid & ~63)) * 8]);
        }
    };

    STAGE(0, 0);
    __syncthreads();
    int cur = 0;
    for (int kt = 0; kt < nt; ++kt) {
        if (kt + 1 < nt) STAGE(cur ^ 1, kt + 1);

        // S^T tile: Sf[nf][v] = S[q=r16][k = nf*16 + kb*4 + v]   (swapped mfma)
        f32x4 Sf[4] = {};
        __builtin_amdgcn_s_setprio(1);
        #pragma unroll
        for (int nf = 0; nf < 4; ++nf) {
            int krow = nf * 16 + r16;
            #pragma unroll
            for (int ksv = 0; ksv < 4; ++ksv) {
                int blk = (ksv * 4 + kb) ^ (krow & 7);
                short8v kf = __builtin_bit_cast(short8v,
                    *(const ushort8v*)&Ks[cur][krow * 128 + blk * 8]);
                Sf[nf] = __builtin_amdgcn_mfma_f32_16x16x32_bf16(kf, qf[ksv], Sf[nf], 0, 0, 0);
            }
        }
        __builtin_amdgcn_s_setprio(0);

        if (kt >= 64) {  // causal mask within the new segment (per-lane compare)
            const int kn0 = (kt - 64) * 64 + kb * 4;
            const int qn = qt * 64 + w * 16 + r16;
            #pragma unroll
            for (int nf = 0; nf < 4; ++nf)
                #pragma unroll
                for (int v = 0; v < 4; ++v)
                    if (kn0 + nf * 16 + v > qn) Sf[nf][v] = -3.0e38f;
        }

        // row max: local tree over 16 regs + 2 cross-kb shuffles
        float mx;
        {
            f32x4 t4 = Sf[0];
            t4 = __builtin_elementwise_max(t4, Sf[1]);
            f32x4 u4 = __builtin_elementwise_max(Sf[2], Sf[3]);
            t4 = __builtin_elementwise_max(t4, u4);
            mx = fmaxf(fmaxf(t4[0], t4[1]), fmaxf(t4[2], t4[3]));
            mx = fmaxf(mx, __shfl_xor(mx, 16, 64));
            mx = fmaxf(mx, __shfl_xor(mx, 32, 64));
        }
        // defer-max: rescale only when some row grew past m+8
        if (__ballot(mx > m_i + 8.f)) {
            float mnew = fmaxf(m_i, mx);
            float alpha = __expf(m_i - mnew);
            m_i = mnew;
            l_i *= alpha;
            #pragma unroll
            for (int v = 0; v < 4; ++v) {
                float av = __shfl(alpha, kb * 4 + v, 64);  // alpha for q=kb*4+v
                #pragma unroll
                for (int of = 0; of < 8; ++of) Of[of][v] *= av;
            }
        }
        // P = exp(S - m), per-lane partial l
        #pragma unroll
        for (int nf = 0; nf < 4; ++nf) {
            float s0 = __expf(Sf[nf][0] - m_i);
            float s1 = __expf(Sf[nf][1] - m_i);
            float s2 = __expf(Sf[nf][2] - m_i);
            float s3 = __expf(Sf[nf][3] - m_i);
            Sf[nf][0] = s0; Sf[nf][1] = s1; Sf[nf][2] = s2; Sf[nf][3] = s3;
            l_i += (s0 + s1) + (s2 + s3);
        }

        // pack P pairs (k even/odd) -> u32, write to Pl row r16 (wave-private)
        #pragma unroll
        for (int nf = 0; nf < 4; ++nf) {
            u32 p0, p1;
            asm("v_cvt_pk_bf16_f32 %0, %1, %2" : "=v"(p0) : "v"(Sf[nf][0]), "v"(Sf[nf][1]));
            asm("v_cvt_pk_bf16_f32 %0, %1, %2" : "=v"(p1) : "v"(Sf[nf][2]), "v"(Sf[nf][3]));
            Pl[w][r16][nf * 8 + kb * 2 + 0] = p0;
            Pl[w][r16][nf * 8 + kb * 2 + 1] = p1;
        }

        // O += P V   (P as A-operand: lane r16 = q-row, k = kb*8+e)
        __builtin_amdgcn_s_setprio(1);
        #pragma unroll
        for (int ka = 0; ka < 2; ++ka) {
            short8v pf = __builtin_bit_cast(short8v,
                *(const ushort8v*)&Pl[w][r16][ka * 16 + kb * 4]);
            #pragma unroll
            for (int of = 0; of < 8; ++of) {
                int vrow = of * 16 + r16;
                int blk = (ka * 4 + kb) ^ (vrow & 7);
                short8v vf = __builtin_bit_cast(short8v,
                    *(const ushort8v*)&Vl[cur][vrow * 64 + blk * 8]);
                Of[of] = __builtin_amdgcn_mfma_f32_16x16x32_bf16(pf, vf, Of[of], 0, 0, 0);
            }
        }
        __builtin_amdgcn_s_setprio(0);

        __syncthreads();
        cur ^= 1;
    }

    // epilogue: reduce l across kb groups, gather per-output-row inverse
    float lt = l_i;
    lt += __shfl_xor(lt, 16, 64);
    lt += __shfl_xor(lt, 32, 64);
    float linv = 1.0f / lt;
    float invl[4];
    #pragma unroll
    for (int v = 0; v < 4; ++v) invl[v] = __shfl(linv, kb * 4 + v, 64);
    #pragma unroll
    for (int of = 0; of < 8; ++of)
        #pragma unroll
        for (int v = 0; v < 4; ++v) {
            int qrow = qt * 64 + w * 16 + kb * 4 + v;
            int d = of * 16 + r16;
            yb[(size_t)(b * 512 + qrow) * 2048 + h * 128 + d] = f2bf(Of[of][v] * invl[v]);
        }
}

// ---------------------------------------------------------------------------
extern "C" void kernel_launch(void* const* d_in, const int* in_sizes, int n_in,
                              void* d_out, int out_size, void* d_ws, size_t ws_size,
                              hipStream_t stream) {
    (void)in_sizes; (void)n_in; (void)out_size; (void)ws_size;
    const float* x   = (const float*)d_in[0];
    const int*   kq  = (const int*)d_in[1];
    const int*   vq  = (const int*)d_in[2];
    const float* ks  = (const float*)d_in[3];
    const float* vs  = (const float*)d_in[4];
    const float* Wq  = (const float*)d_in[5];
    const float* Wk  = (const float*)d_in[6];
    const float* Wv  = (const float*)d_in[7];
    const float* Wo  = (const float*)d_in[8];

    float* out  = (float*)d_out;
    float* y_o  = out;
    float* oktq = out + 4194304;
    float* ovtq = out + 37748736;
    float* oksc = out + 71303168;
    float* ovsc = out + 71565312;

    char* wsb = (char*)d_ws;
    u16* kcb = (u16*)(wsb);                       // 75.5 MB: [64][4608][128] bf16
    u16* vtb = (u16*)(wsb + 75497472);            // 75.5 MB: [64][128][4608] bf16
    u16* xb  = (u16*)(wsb + 150994944);           // 8 MB
    u16* wb  = (u16*)(wsb + 159383552);           // 8 MB (reused per GEMM)
    u16* qbf = (u16*)(wsb + 167772160);           // 8 MB
    u16* vnb = (u16*)(wsb + 176160768);           // 8 MB
    u16* ybf = (u16*)(wsb + 184549376);           // 8 MB

    const float rscale = 0.08838834764831845f;    // 1/sqrt(128)
    const int n8 = 2048 * 2048 / 8;

    prep_cache_kernel<<<4096, 256, 0, stream>>>(kq, vq, ks, vs, kcb, vtb,
                                                oktq, ovtq, oksc, ovsc);
    convert_kernel<<<2048, 256, 0, stream>>>(x, xb, 1.0f, n8);
    convert_kernel<<<2048, 256, 0, stream>>>(Wq, wb, rscale, n8);
    gemm_bf16_kernel<0><<<512, 256, 0, stream>>>(xb, wb, qbf);
    convert_kernel<<<2048, 256, 0, stream>>>(Wk, wb, 1.0f, n8);
    gemm_bf16_kernel<1><<<512, 256, 0, stream>>>(xb, wb, kcb);
    convert_kernel<<<2048, 256, 0, stream>>>(Wv, wb, 1.0f, n8);
    gemm_bf16_kernel<2><<<512, 256, 0, stream>>>(xb, wb, vnb);
    quant_new_kernel<<<512, 256, 0, stream>>>(kcb, vnb, vtb,
                                              oktq, ovtq, oksc, ovsc);
    attn_kernel<<<512, 256, 0, stream>>>(qbf, kcb, vtb, ybf);
    convert_kernel<<<2048, 256, 0, stream>>>(Wo, wb, 1.0f, n8);
    gemm_bf16_kernel<3><<<512, 256, 0, stream>>>(ybf, wb, y_o);
}